// Round 1
// baseline (3387.839 us; speedup 1.0000x reference)
//
#include <hip/hip_runtime.h>
#include <math.h>

#define B_    32
#define NT    64
#define NS    48
#define LI    36
#define D_    1024
#define H_    1024
#define NPAIR 1128            // 48*47/2
#define ROWS  (B_*NPAIR)      // 36096
#define NEGV  -9.0e9f

// ---------------------------------------------------------------------------
// C[M,N] = A[M,K] @ Bm[N,K]^T   (both row-major, M,N mult of 64, K mult of 16)
// ---------------------------------------------------------------------------
__global__ __launch_bounds__(256) void gemm_bt64(
    const float* __restrict__ A, const float* __restrict__ Bm,
    float* __restrict__ C, int M, int N, int K) {
  __shared__ float sA[64][17];
  __shared__ float sB[64][17];
  const int tid = threadIdx.x;
  const int tx = tid & 15, ty = tid >> 4;
  const int rowBase = blockIdx.y << 6, colBase = blockIdx.x << 6;
  const int lr = tid >> 2, lk = (tid & 3) << 2;
  float acc[4][4] = {};
  const float* pA = A + (size_t)(rowBase + lr) * K + lk;
  const float* pB = Bm + (size_t)(colBase + lr) * K + lk;
  for (int k0 = 0; k0 < K; k0 += 16) {
    float4 va = *(const float4*)(pA + k0);
    float4 vb = *(const float4*)(pB + k0);
    sA[lr][lk+0] = va.x; sA[lr][lk+1] = va.y; sA[lr][lk+2] = va.z; sA[lr][lk+3] = va.w;
    sB[lr][lk+0] = vb.x; sB[lr][lk+1] = vb.y; sB[lr][lk+2] = vb.z; sB[lr][lk+3] = vb.w;
    __syncthreads();
#pragma unroll
    for (int kk = 0; kk < 16; ++kk) {
      float a[4], b[4];
#pragma unroll
      for (int i = 0; i < 4; ++i) a[i] = sA[ty*4+i][kk];
#pragma unroll
      for (int j = 0; j < 4; ++j) b[j] = sB[tx*4+j][kk];
#pragma unroll
      for (int i = 0; i < 4; ++i)
#pragma unroll
        for (int j = 0; j < 4; ++j) acc[i][j] += a[i]*b[j];
    }
    __syncthreads();
  }
#pragma unroll
  for (int i = 0; i < 4; ++i)
#pragma unroll
    for (int j = 0; j < 4; ++j)
      C[(size_t)(rowBase + ty*4 + i)*N + colBase + tx*4 + j] = acc[i][j];
}

// ---------------------------------------------------------------------------
// C[M,N] = A[M,K] @ W[K,N]   (row-major, M,N mult of 64, K mult of 16)
// ---------------------------------------------------------------------------
__global__ __launch_bounds__(256) void gemm_nn64(
    const float* __restrict__ A, const float* __restrict__ W,
    float* __restrict__ C, int M, int N, int K) {
  __shared__ float sA[64][17];
  __shared__ float sW[16][65];
  const int tid = threadIdx.x;
  const int tx = tid & 15, ty = tid >> 4;
  const int rowBase = blockIdx.y << 6, colBase = blockIdx.x << 6;
  const int lr = tid >> 2, lk = (tid & 3) << 2;     // A-tile load coords
  const int wk = tid >> 4, wn = (tid & 15) << 2;    // W-tile load coords
  float acc[4][4] = {};
  const float* pA = A + (size_t)(rowBase + lr) * K + lk;
  for (int k0 = 0; k0 < K; k0 += 16) {
    float4 va = *(const float4*)(pA + k0);
    float4 vw = *(const float4*)&W[(size_t)(k0 + wk) * N + colBase + wn];
    sA[lr][lk+0] = va.x; sA[lr][lk+1] = va.y; sA[lr][lk+2] = va.z; sA[lr][lk+3] = va.w;
    sW[wk][wn+0] = vw.x; sW[wk][wn+1] = vw.y; sW[wk][wn+2] = vw.z; sW[wk][wn+3] = vw.w;
    __syncthreads();
#pragma unroll
    for (int kk = 0; kk < 16; ++kk) {
      float a[4], b[4];
#pragma unroll
      for (int i = 0; i < 4; ++i) a[i] = sA[ty*4+i][kk];
#pragma unroll
      for (int j = 0; j < 4; ++j) b[j] = sW[kk][tx*4+j];
#pragma unroll
      for (int i = 0; i < 4; ++i)
#pragma unroll
        for (int j = 0; j < 4; ++j) acc[i][j] += a[i]*b[j];
    }
    __syncthreads();
  }
#pragma unroll
  for (int i = 0; i < 4; ++i)
#pragma unroll
    for (int j = 0; j < 4; ++j)
      C[(size_t)(rowBase + ty*4 + i)*N + colBase + tx*4 + j] = acc[i][j];
}

// ---------------------------------------------------------------------------
// GEMM1c: h1[r - rowStart, :] = relu( (span_fi .* span_si) @ W1c
//                                     + A1[b,fi,:] + B1[b,si,:] + b1 )
// rows r are global pair rows, r = b*NPAIR + p, p -> (fi,si) triu order.
// ---------------------------------------------------------------------------
__global__ __launch_bounds__(256) void gemm1c(
    const float* __restrict__ spans, const float* __restrict__ W1c,
    const float* __restrict__ A1, const float* __restrict__ B1,
    const float* __restrict__ b1, float* __restrict__ h1,
    int rowStart, int rowsInChunk) {
  __shared__ float sA[64][17];
  __shared__ float sW[16][65];
  __shared__ int sFi[64], sSi[64], sBb[64];
  const int tid = threadIdx.x;
  const int base = rowStart + (blockIdx.y << 6);
  const int rowEnd = rowStart + rowsInChunk;
  if (tid < 64) {
    int row = base + tid;
    int fi = 0, si = 1, bb = 0;
    if (row < rowEnd) {
      bb = row / NPAIR;
      int p = row - bb * NPAIR;
      int cum = 0, f = 0;
      while (true) { int cnt = NS - 1 - f; if (p < cum + cnt) break; cum += cnt; ++f; }
      fi = f; si = f + 1 + (p - cum);
    }
    sFi[tid] = fi; sSi[tid] = si; sBb[tid] = bb;
  }
  __syncthreads();
  const int tx = tid & 15, ty = tid >> 4;
  const int colBase = blockIdx.x << 6;
  const int lr = tid >> 2, lk = (tid & 3) << 2;
  const int wk = tid >> 4, wn = (tid & 15) << 2;
  const bool rowOk = (base + lr) < rowEnd;
  const float* pf = spans + ((size_t)sBb[lr] * NS + sFi[lr]) * D_ + lk;
  const float* ps = spans + ((size_t)sBb[lr] * NS + sSi[lr]) * D_ + lk;
  float acc[4][4] = {};
  for (int k0 = 0; k0 < D_; k0 += 16) {
    float4 x = make_float4(0,0,0,0), y = make_float4(0,0,0,0);
    if (rowOk) { x = *(const float4*)(pf + k0); y = *(const float4*)(ps + k0); }
    float4 vw = *(const float4*)&W1c[(size_t)(k0 + wk) * H_ + colBase + wn];
    sA[lr][lk+0] = x.x*y.x; sA[lr][lk+1] = x.y*y.y; sA[lr][lk+2] = x.z*y.z; sA[lr][lk+3] = x.w*y.w;
    sW[wk][wn+0] = vw.x; sW[wk][wn+1] = vw.y; sW[wk][wn+2] = vw.z; sW[wk][wn+3] = vw.w;
    __syncthreads();
#pragma unroll
    for (int kk = 0; kk < 16; ++kk) {
      float a[4], b[4];
#pragma unroll
      for (int i = 0; i < 4; ++i) a[i] = sA[ty*4+i][kk];
#pragma unroll
      for (int j = 0; j < 4; ++j) b[j] = sW[kk][tx*4+j];
#pragma unroll
      for (int i = 0; i < 4; ++i)
#pragma unroll
        for (int j = 0; j < 4; ++j) acc[i][j] += a[i]*b[j];
    }
    __syncthreads();
  }
#pragma unroll
  for (int i = 0; i < 4; ++i) {
    int tr = ty*4 + i;
    int r = base + tr;
    if (r < rowEnd) {
      const float* a1p = A1 + ((size_t)sBb[tr] * NS + sFi[tr]) * H_;
      const float* b1p = B1 + ((size_t)sBb[tr] * NS + sSi[tr]) * H_;
#pragma unroll
      for (int j = 0; j < 4; ++j) {
        int c = colBase + tx*4 + j;
        float v = acc[i][j] + a1p[c] + b1p[c] + b1[c];
        h1[(size_t)(r - rowStart) * H_ + c] = fmaxf(v, 0.f);
      }
    }
  }
}

// ---------------------------------------------------------------------------
// GEMM2 + fused W3 epilogue: scores[r] += sum_j relu(h1[r]@W2[:,j] + b2[j])*W3[j]
// ---------------------------------------------------------------------------
__global__ __launch_bounds__(256) void gemm2(
    const float* __restrict__ h1, const float* __restrict__ W2,
    const float* __restrict__ b2, const float* __restrict__ W3,
    float* __restrict__ scores, int rowStart, int rowsInChunk) {
  __shared__ float sA[64][17];
  __shared__ float sW[16][65];
  __shared__ float sRed[64][17];
  const int tid = threadIdx.x;
  const int tx = tid & 15, ty = tid >> 4;
  const int localBase = blockIdx.y << 6;
  const int colBase = blockIdx.x << 6;
  const int lr = tid >> 2, lk = (tid & 3) << 2;
  const int wk = tid >> 4, wn = (tid & 15) << 2;
  const bool rowOk = (localBase + lr) < rowsInChunk;
  float acc[4][4] = {};
  const float* pA = h1 + (size_t)(localBase + lr) * H_ + lk;
  for (int k0 = 0; k0 < H_; k0 += 16) {
    float4 va = make_float4(0,0,0,0);
    if (rowOk) va = *(const float4*)(pA + k0);
    float4 vw = *(const float4*)&W2[(size_t)(k0 + wk) * H_ + colBase + wn];
    sA[lr][lk+0] = va.x; sA[lr][lk+1] = va.y; sA[lr][lk+2] = va.z; sA[lr][lk+3] = va.w;
    sW[wk][wn+0] = vw.x; sW[wk][wn+1] = vw.y; sW[wk][wn+2] = vw.z; sW[wk][wn+3] = vw.w;
    __syncthreads();
#pragma unroll
    for (int kk = 0; kk < 16; ++kk) {
      float a[4], b[4];
#pragma unroll
      for (int i = 0; i < 4; ++i) a[i] = sA[ty*4+i][kk];
#pragma unroll
      for (int j = 0; j < 4; ++j) b[j] = sW[kk][tx*4+j];
#pragma unroll
      for (int i = 0; i < 4; ++i)
#pragma unroll
        for (int j = 0; j < 4; ++j) acc[i][j] += a[i]*b[j];
    }
    __syncthreads();
  }
  float rsum[4];
#pragma unroll
  for (int i = 0; i < 4; ++i) {
    rsum[i] = 0.f;
#pragma unroll
    for (int j = 0; j < 4; ++j) {
      int c = colBase + tx*4 + j;
      float v = acc[i][j] + b2[c];
      v = fmaxf(v, 0.f);
      rsum[i] += v * W3[c];
    }
    sRed[ty*4 + i][tx] = rsum[i];
  }
  __syncthreads();
  if (tid < 64) {
    int lrow = localBase + tid;
    if (lrow < rowsInChunk) {
      float s = 0.f;
#pragma unroll
      for (int t = 0; t < 16; ++t) s += sRed[tid][t];
      atomicAdd(&scores[rowStart + lrow], s);
    }
  }
}

__global__ void init_scores(float* __restrict__ scores, const float* __restrict__ b3) {
  int idx = blockIdx.x * 256 + threadIdx.x;
  if (idx < ROWS) scores[idx] = b3[0];
}

// ---------------------------------------------------------------------------
// Sentence scores S[i,j]: masked bidirectional softmax-weighted dot means.
// exp(NEG) underflows to 0 in f32, so this is an exact masked softmax.
// ---------------------------------------------------------------------------
__global__ __launch_bounds__(64) void sent_kernel(
    const float* __restrict__ dotTI, const float* __restrict__ tmask,
    const float* __restrict__ imask, float* __restrict__ S) {
  const int i = blockIdx.y, j = blockIdx.x, t = threadIdx.x;
  __shared__ float red1[64], red2[64];
  const int stride = B_ * LI;
  // term1: thread t = text row n; softmax over valid l, weighted mean of dot
  float e1 = 0.f;
  {
    float tm = tmask[i*NT + t];
    if (tm != 0.f) {
      const float* row = dotTI + (size_t)(i*NT + t) * stride + j*LI;
      float m = -INFINITY;
      for (int l = 0; l < LI; ++l) if (imask[j*LI + l] != 0.f) m = fmaxf(m, row[l]);
      float z = 0.f, w = 0.f;
      for (int l = 0; l < LI; ++l) if (imask[j*LI + l] != 0.f) {
        float d = row[l];
        float p = expf(d - m);
        z += p; w += p * d;
      }
      e1 = w / z;
    }
  }
  red1[t] = e1;
  // term2: thread t = image col l (t < 36); softmax over valid n
  float e2 = 0.f;
  if (t < LI) {
    float im = imask[j*LI + t];
    if (im != 0.f) {
      const float* col = dotTI + (size_t)(i*NT) * stride + j*LI + t;
      float m = -INFINITY;
      for (int n = 0; n < NT; ++n) if (tmask[i*NT + n] != 0.f) m = fmaxf(m, col[(size_t)n*stride]);
      float z = 0.f, w = 0.f;
      for (int n = 0; n < NT; ++n) if (tmask[i*NT + n] != 0.f) {
        float d = col[(size_t)n*stride];
        float p = expf(d - m);
        z += p; w += p * d;
      }
      e2 = w / z;
    }
  }
  red2[t] = e2;
  __syncthreads();
  if (t == 0) {
    float s1 = 0.f, s2 = 0.f, cn = 0.f, cl = 0.f;
    for (int n = 0; n < NT; ++n) { s1 += red1[n]; cn += tmask[i*NT + n]; }
    for (int l = 0; l < LI; ++l) { s2 += red2[l]; cl += imask[j*LI + l]; }
    S[i*B_ + j] = s1 / cn + s2 / cl;
  }
}

// loss = -(sum_i [S_ii - lse(row_i)] + sum_i [S_ii - lse(col_i)]) / B
__global__ __launch_bounds__(64) void loss_kernel(
    const float* __restrict__ S, float* __restrict__ out) {
  __shared__ float sS[B_][B_ + 1];
  __shared__ float acc[B_];
  const int t = threadIdx.x;
  for (int e = t; e < B_*B_; e += 64) sS[e / B_][e % B_] = S[e];
  __syncthreads();
  if (t < B_) {
    float m = -INFINITY;
    for (int j = 0; j < B_; ++j) m = fmaxf(m, sS[t][j]);
    float z = 0.f;
    for (int j = 0; j < B_; ++j) z += expf(sS[t][j] - m);
    float lr = m + logf(z);
    float m2 = -INFINITY;
    for (int i = 0; i < B_; ++i) m2 = fmaxf(m2, sS[i][t]);
    float z2 = 0.f;
    for (int i = 0; i < B_; ++i) z2 += expf(sS[i][t] - m2);
    float lc = m2 + logf(z2);
    acc[t] = 2.f * sS[t][t] - lr - lc;
  }
  __syncthreads();
  if (t == 0) {
    float s = 0.f;
    for (int i = 0; i < B_; ++i) s += acc[i];
    out[0] = -s / (float)B_;
  }
}

// grounding[b,n,l] = mask ? span[b,n].image[b,l] : NEG
__global__ __launch_bounds__(256) void grounding_kernel(
    const float* __restrict__ span, const float* __restrict__ img,
    const float* __restrict__ smask, const float* __restrict__ imask,
    float* __restrict__ outg) {
  const int b = blockIdx.x, tid = threadIdx.x;
  __shared__ float sS[NS][33];
  __shared__ float sI[LI][33];
  float acc[7] = {0,0,0,0,0,0,0};
  for (int k0 = 0; k0 < D_; k0 += 32) {
    for (int e = tid; e < NS*32; e += 256) {
      int n = e >> 5, kk = e & 31;
      sS[n][kk] = span[((size_t)b*NS + n)*D_ + k0 + kk];
    }
    for (int e = tid; e < LI*32; e += 256) {
      int l = e >> 5, kk = e & 31;
      sI[l][kk] = img[((size_t)b*LI + l)*D_ + k0 + kk];
    }
    __syncthreads();
#pragma unroll
    for (int q = 0; q < 7; ++q) {
      int o = tid + q*256;
      if (o < NS*LI) {
        int n = o / LI, l = o % LI;
        float s = 0.f;
#pragma unroll
        for (int kk = 0; kk < 32; ++kk) s += sS[n][kk] * sI[l][kk];
        acc[q] += s;
      }
    }
    __syncthreads();
  }
#pragma unroll
  for (int q = 0; q < 7; ++q) {
    int o = tid + q*256;
    if (o < NS*LI) {
      int n = o / LI, l = o % LI;
      float v = (smask[b*NS + n] * imask[b*LI + l] != 0.f) ? acc[q] : NEGV;
      outg[(size_t)b*NS*LI + o] = v;
    }
  }
}

extern "C" void kernel_launch(void* const* d_in, const int* in_sizes, int n_in,
                              void* d_out, int out_size, void* d_ws, size_t ws_size,
                              hipStream_t stream) {
  const float* text  = (const float*)d_in[0];
  const float* span  = (const float*)d_in[1];
  const float* img   = (const float*)d_in[2];
  const float* tmask = (const float*)d_in[3];
  const float* smask = (const float*)d_in[4];
  const float* imask = (const float*)d_in[5];
  const float* W1    = (const float*)d_in[6];
  const float* b1    = (const float*)d_in[7];
  const float* W2    = (const float*)d_in[8];
  const float* b2    = (const float*)d_in[9];
  const float* W3    = (const float*)d_in[10];
  const float* b3    = (const float*)d_in[11];

  float* out     = (float*)d_out;
  float* outLoss = out;
  float* outG    = out + 1;
  float* outT    = out + 1 + (size_t)B_*NS*LI;

  // workspace layout
  float* dotTI = (float*)d_ws;                           // 2048*1152 f32
  float* S     = dotTI + (size_t)(B_*NT)*(B_*LI);        // 1024 f32
  float* A1    = S + B_*B_;                              // 1536*1024 f32
  float* B1    = A1 + (size_t)B_*NS*H_;                  // 1536*1024 f32
  float* h1    = B1 + (size_t)B_*NS*H_;                  // chunked
  size_t fixedBytes = (size_t)((char*)h1 - (char*)d_ws);
  size_t avail = (ws_size > fixedBytes) ? ws_size - fixedBytes : 0;
  long long chunkRows = (long long)(avail / (H_ * sizeof(float)));
  if (chunkRows > ROWS) chunkRows = ROWS;
  chunkRows &= ~63LL;
  if (chunkRows < 64) chunkRows = 64;  // assumes ws_size >= ~22.3 MB

  const float* W1a = W1;
  const float* W1b = W1 + (size_t)D_*H_;
  const float* W1c = W1 + (size_t)2*D_*H_;

  // 1) text-image dot matrix -> S -> loss
  gemm_bt64<<<dim3((B_*LI)/64, (B_*NT)/64), 256, 0, stream>>>(
      text, img, dotTI, B_*NT, B_*LI, D_);
  sent_kernel<<<dim3(B_, B_), 64, 0, stream>>>(dotTI, tmask, imask, S);
  loss_kernel<<<1, 64, 0, stream>>>(S, outLoss);

  // 2) grounding scores (diagonal att)
  grounding_kernel<<<B_, 256, 0, stream>>>(span, img, smask, imask, outG);

  // 3) pairwise MLP: factor first/second parts of W1, chunk pair rows
  gemm_nn64<<<dim3(H_/64, (B_*NS)/64), 256, 0, stream>>>(span, W1a, A1, B_*NS, H_, D_);
  gemm_nn64<<<dim3(H_/64, (B_*NS)/64), 256, 0, stream>>>(span, W1b, B1, B_*NS, H_, D_);
  init_scores<<<(ROWS + 255)/256, 256, 0, stream>>>(outT, b3);
  for (long long rs = 0; rs < ROWS; rs += chunkRows) {
    int rows = (int)((ROWS - rs < chunkRows) ? (ROWS - rs) : chunkRows);
    dim3 g(H_/64, (rows + 63)/64);
    gemm1c<<<g, 256, 0, stream>>>(span, W1c, A1, B1, b1, h1, (int)rs, rows);
    gemm2<<<g, 256, 0, stream>>>(h1, W2, b2, W3, outT, (int)rs, rows);
  }
}

// Round 2
// 599.569 us; speedup vs baseline: 5.6505x; 5.6505x over previous
//
#include <hip/hip_runtime.h>
#include <math.h>
#include <stdint.h>

#define B_    32
#define NT    64
#define NS    48
#define LI    36
#define D_    1024
#define H_    1024
#define NPAIR 1128            // 48*47/2
#define ROWS  (B_*NPAIR)      // 36096
#define NEGV  -9.0e9f
#define CHUNK 12032           // 94*128; 3 chunks cover 36096

typedef _Float16 half8 __attribute__((ext_vector_type(8)));
typedef float floatx4 __attribute__((ext_vector_type(4)));
typedef __attribute__((address_space(3))) uint32_t lds_u32;
typedef __attribute__((address_space(1))) const uint32_t glb_u32;

// ---------------------------------------------------------------------------
// Templated MFMA GEMM: C[M,N] = A[M,K] @ Bt[N,K]^T, f16 in, f32 acc.
// 128x128 tile, BK=32, 4 waves, 16x16x32_f16 (m97 structure).
// EPI 0: store f32 C. EPI 1: h1 = relu(C + A1 + B1 + b1) as f16.
// EPI 2: scores += sum_c relu(C + b2[c]) * W3[c]  (atomicAdd per row)
// ---------------------------------------------------------------------------
template<int EPI>
__global__ __launch_bounds__(256) void mfma_gemm(
    const _Float16* __restrict__ A, const _Float16* __restrict__ Bt,
    float* __restrict__ Cf, _Float16* __restrict__ h1out,
    float* __restrict__ scores, const float* __restrict__ AB1,
    const float* __restrict__ bias, const float* __restrict__ W3,
    const int* __restrict__ idxF, const int* __restrict__ idxS,
    int N, int K, int rowStart) {
  __shared__ __align__(16) _Float16 sA[128 * 32];
  __shared__ __align__(16) _Float16 sB[128 * 32];
  __shared__ float sRed[128][2];
  const int tid = threadIdx.x;
  const int lane = tid & 63;
  const int wave = tid >> 6;
  const int wr = wave >> 1, wc = wave & 1;
  const int l15 = lane & 15, l16 = lane >> 4;
  const int rowBase = blockIdx.y * 128, colBase = blockIdx.x * 128;

  const int stRow = tid >> 2;            // 0..63
  const int stCol = (tid & 3) << 3;      // halves: 0,8,16,24
  const _Float16* gA = A + (size_t)(rowBase + stRow) * K + stCol;
  const _Float16* gB = Bt + (size_t)(colBase + stRow) * K + stCol;
  _Float16* lA = sA + tid * 8;
  _Float16* lB = sB + tid * 8;

  floatx4 acc[4][4] = {};
  for (int k0 = 0; k0 < K; k0 += 32) {
    __builtin_amdgcn_global_load_lds((glb_u32*)(gA + k0),           (lds_u32*)lA,             16, 0, 0);
    __builtin_amdgcn_global_load_lds((glb_u32*)(gA + 64 * K + k0),  (lds_u32*)(lA + 64 * 32), 16, 0, 0);
    __builtin_amdgcn_global_load_lds((glb_u32*)(gB + k0),           (lds_u32*)lB,             16, 0, 0);
    __builtin_amdgcn_global_load_lds((glb_u32*)(gB + 64 * K + k0),  (lds_u32*)(lB + 64 * 32), 16, 0, 0);
    __syncthreads();
    half8 aF[4], bF[4];
#pragma unroll
    for (int i = 0; i < 4; ++i)
      aF[i] = *(const half8*)&sA[(wr * 64 + i * 16 + l15) * 32 + l16 * 8];
#pragma unroll
    for (int j = 0; j < 4; ++j)
      bF[j] = *(const half8*)&sB[(wc * 64 + j * 16 + l15) * 32 + l16 * 8];
#pragma unroll
    for (int i = 0; i < 4; ++i)
#pragma unroll
      for (int j = 0; j < 4; ++j)
        acc[i][j] = __builtin_amdgcn_mfma_f32_16x16x32_f16(aF[i], bF[j], acc[i][j], 0, 0, 0);
    __syncthreads();
  }

  if (EPI == 0) {
#pragma unroll
    for (int i = 0; i < 4; ++i)
#pragma unroll
      for (int q = 0; q < 4; ++q) {
        int r = rowBase + wr * 64 + i * 16 + l16 * 4 + q;
#pragma unroll
        for (int j = 0; j < 4; ++j) {
          int c = colBase + wc * 64 + j * 16 + l15;
          Cf[(size_t)r * N + c] = acc[i][j][q];
        }
      }
  } else if (EPI == 1) {
    int cols[4]; float bv[4];
#pragma unroll
    for (int j = 0; j < 4; ++j) {
      cols[j] = colBase + wc * 64 + j * 16 + l15;
      bv[j] = bias[cols[j]];
    }
#pragma unroll
    for (int i = 0; i < 4; ++i)
#pragma unroll
      for (int q = 0; q < 4; ++q) {
        int rG = rowStart + rowBase + wr * 64 + i * 16 + l16 * 4 + q;
        const float* ap = AB1 + (size_t)idxF[rG] * 2048;
        const float* bp = AB1 + (size_t)idxS[rG] * 2048 + 1024;
#pragma unroll
        for (int j = 0; j < 4; ++j) {
          int c = cols[j];
          float v = acc[i][j][q] + ap[c] + bp[c] + bv[j];
          h1out[(size_t)rG * 1024 + c] = (_Float16)fmaxf(v, 0.f);
        }
      }
  } else {
    float bv[4], wv[4];
#pragma unroll
    for (int j = 0; j < 4; ++j) {
      int c = colBase + wc * 64 + j * 16 + l15;
      bv[j] = bias[c];
      wv[j] = W3[c];
    }
#pragma unroll
    for (int i = 0; i < 4; ++i)
#pragma unroll
      for (int q = 0; q < 4; ++q) {
        float s = 0.f;
#pragma unroll
        for (int j = 0; j < 4; ++j) s += fmaxf(acc[i][j][q] + bv[j], 0.f) * wv[j];
        s += __shfl_xor(s, 1); s += __shfl_xor(s, 2);
        s += __shfl_xor(s, 4); s += __shfl_xor(s, 8);
        if (l15 == 0) sRed[wr * 64 + i * 16 + l16 * 4 + q][wc] = s;
      }
    __syncthreads();
    if (tid < 128)
      atomicAdd(&scores[rowStart + rowBase + tid], sRed[tid][0] + sRed[tid][1]);
  }
}

// f32 -> f16 copy (n8 = elems/8)
__global__ __launch_bounds__(256) void cvt_f16(
    const float* __restrict__ in, _Float16* __restrict__ out, long long n8) {
  long long i = (long long)blockIdx.x * 256 + threadIdx.x;
  if (i >= n8) return;
  const float4* p = (const float4*)in + i * 2;
  float4 a = p[0], b = p[1];
  half8 h;
  h[0] = (_Float16)a.x; h[1] = (_Float16)a.y; h[2] = (_Float16)a.z; h[3] = (_Float16)a.w;
  h[4] = (_Float16)b.x; h[5] = (_Float16)b.y; h[6] = (_Float16)b.z; h[7] = (_Float16)b.w;
  *(half8*)(out + i * 8) = h;
}

// out[n][k] = (f16) in[k][n], 1024x1024
__global__ __launch_bounds__(256) void transpose_cvt(
    const float* __restrict__ in, _Float16* __restrict__ out) {
  __shared__ float t[32][33];
  const int tx = threadIdx.x & 31, ty = threadIdx.x >> 5;
  const int k0 = blockIdx.y * 32, n0 = blockIdx.x * 32;
#pragma unroll
  for (int q = 0; q < 4; ++q)
    t[ty + q * 8][tx] = in[(size_t)(k0 + ty + q * 8) * 1024 + n0 + tx];
  __syncthreads();
#pragma unroll
  for (int q = 0; q < 4; ++q)
    out[(size_t)(n0 + ty + q * 8) * 1024 + k0 + tx] = (_Float16)t[tx][ty + q * 8];
}

__global__ __launch_bounds__(256) void idx_init(int* __restrict__ idxF, int* __restrict__ idxS) {
  int r = blockIdx.x * 256 + threadIdx.x;
  if (r >= ROWS) return;
  int bb = r / NPAIR, p = r - bb * NPAIR;
  int cum = 0, f = 0;
  while (true) { int cnt = NS - 1 - f; if (p < cum + cnt) break; cum += cnt; ++f; }
  idxF[r] = bb * NS + f;
  idxS[r] = bb * NS + f + 1 + (p - cum);
}

// P[rL][k] = (f16)(span[idxF] * span[idxS]), 8 elems/thread
__global__ __launch_bounds__(256) void build_p(
    const float* __restrict__ span, const int* __restrict__ idxF,
    const int* __restrict__ idxS, _Float16* __restrict__ P,
    int rowStart, int rowsInChunk) {
  long long i = (long long)blockIdx.x * 256 + threadIdx.x;
  long long tot = (long long)rowsInChunk * 128;
  if (i >= tot) return;
  int rL = (int)(i >> 7);
  int k8 = (int)(i & 127) << 3;
  int rG = rowStart + rL;
  const float4* pf = (const float4*)(span + (size_t)idxF[rG] * 1024 + k8);
  const float4* ps = (const float4*)(span + (size_t)idxS[rG] * 1024 + k8);
  float4 f0 = pf[0], f1 = pf[1], s0 = ps[0], s1 = ps[1];
  half8 h;
  h[0] = (_Float16)(f0.x * s0.x); h[1] = (_Float16)(f0.y * s0.y);
  h[2] = (_Float16)(f0.z * s0.z); h[3] = (_Float16)(f0.w * s0.w);
  h[4] = (_Float16)(f1.x * s1.x); h[5] = (_Float16)(f1.y * s1.y);
  h[6] = (_Float16)(f1.z * s1.z); h[7] = (_Float16)(f1.w * s1.w);
  *(half8*)(P + (size_t)rL * 1024 + k8) = h;
}

__global__ void init_scores(float* __restrict__ scores, const float* __restrict__ b3) {
  int idx = blockIdx.x * 256 + threadIdx.x;
  if (idx < ROWS) scores[idx] = b3[0];
}

// ---------------------------------------------------------------------------
// Sentence scores S[i,j] (exp(NEG)==0 in f32 -> exact masked softmax)
// ---------------------------------------------------------------------------
__global__ __launch_bounds__(64) void sent_kernel(
    const float* __restrict__ dotTI, const float* __restrict__ tmask,
    const float* __restrict__ imask, float* __restrict__ S) {
  const int i = blockIdx.y, j = blockIdx.x, t = threadIdx.x;
  __shared__ float red1[64], red2[64];
  const int stride = B_ * LI;
  float e1 = 0.f;
  {
    float tm = tmask[i * NT + t];
    if (tm != 0.f) {
      const float* row = dotTI + (size_t)(i * NT + t) * stride + j * LI;
      float m = -INFINITY;
      for (int l = 0; l < LI; ++l) if (imask[j * LI + l] != 0.f) m = fmaxf(m, row[l]);
      float z = 0.f, w = 0.f;
      for (int l = 0; l < LI; ++l) if (imask[j * LI + l] != 0.f) {
        float d = row[l], p = expf(d - m);
        z += p; w += p * d;
      }
      e1 = w / z;
    }
  }
  red1[t] = e1;
  float e2 = 0.f;
  if (t < LI) {
    float im = imask[j * LI + t];
    if (im != 0.f) {
      const float* col = dotTI + (size_t)(i * NT) * stride + j * LI + t;
      float m = -INFINITY;
      for (int n = 0; n < NT; ++n) if (tmask[i * NT + n] != 0.f) m = fmaxf(m, col[(size_t)n * stride]);
      float z = 0.f, w = 0.f;
      for (int n = 0; n < NT; ++n) if (tmask[i * NT + n] != 0.f) {
        float d = col[(size_t)n * stride], p = expf(d - m);
        z += p; w += p * d;
      }
      e2 = w / z;
    }
  }
  red2[t] = e2;
  __syncthreads();
  if (t == 0) {
    float s1 = 0.f, s2 = 0.f, cn = 0.f, cl = 0.f;
    for (int n = 0; n < NT; ++n) { s1 += red1[n]; cn += tmask[i * NT + n]; }
    for (int l = 0; l < LI; ++l) { s2 += red2[l]; cl += imask[j * LI + l]; }
    S[i * B_ + j] = s1 / cn + s2 / cl;
  }
}

__global__ __launch_bounds__(64) void loss_kernel(
    const float* __restrict__ S, float* __restrict__ out) {
  __shared__ float sS[B_][B_ + 1];
  __shared__ float acc[B_];
  const int t = threadIdx.x;
  for (int e = t; e < B_ * B_; e += 64) sS[e / B_][e % B_] = S[e];
  __syncthreads();
  if (t < B_) {
    float m = -INFINITY;
    for (int j = 0; j < B_; ++j) m = fmaxf(m, sS[t][j]);
    float z = 0.f;
    for (int j = 0; j < B_; ++j) z += expf(sS[t][j] - m);
    float lr = m + logf(z);
    float m2 = -INFINITY;
    for (int i = 0; i < B_; ++i) m2 = fmaxf(m2, sS[i][t]);
    float z2 = 0.f;
    for (int i = 0; i < B_; ++i) z2 += expf(sS[i][t] - m2);
    float lc = m2 + logf(z2);
    acc[t] = 2.f * sS[t][t] - lr - lc;
  }
  __syncthreads();
  if (t == 0) {
    float s = 0.f;
    for (int i = 0; i < B_; ++i) s += acc[i];
    out[0] = -s / (float)B_;
  }
}

__global__ __launch_bounds__(256) void grounding_kernel(
    const float* __restrict__ span, const float* __restrict__ img,
    const float* __restrict__ smask, const float* __restrict__ imask,
    float* __restrict__ outg) {
  const int b = blockIdx.x, tid = threadIdx.x;
  __shared__ float sS[NS][33];
  __shared__ float sI[LI][33];
  float acc[7] = {0, 0, 0, 0, 0, 0, 0};
  for (int k0 = 0; k0 < D_; k0 += 32) {
    for (int e = tid; e < NS * 32; e += 256) {
      int n = e >> 5, kk = e & 31;
      sS[n][kk] = span[((size_t)b * NS + n) * D_ + k0 + kk];
    }
    for (int e = tid; e < LI * 32; e += 256) {
      int l = e >> 5, kk = e & 31;
      sI[l][kk] = img[((size_t)b * LI + l) * D_ + k0 + kk];
    }
    __syncthreads();
#pragma unroll
    for (int q = 0; q < 7; ++q) {
      int o = tid + q * 256;
      if (o < NS * LI) {
        int n = o / LI, l = o % LI;
        float s = 0.f;
#pragma unroll
        for (int kk = 0; kk < 32; ++kk) s += sS[n][kk] * sI[l][kk];
        acc[q] += s;
      }
    }
    __syncthreads();
  }
#pragma unroll
  for (int q = 0; q < 7; ++q) {
    int o = tid + q * 256;
    if (o < NS * LI) {
      int n = o / LI, l = o % LI;
      float v = (smask[b * NS + n] * imask[b * LI + l] != 0.f) ? acc[q] : NEGV;
      outg[(size_t)b * NS * LI + o] = v;
    }
  }
}

extern "C" void kernel_launch(void* const* d_in, const int* in_sizes, int n_in,
                              void* d_out, int out_size, void* d_ws, size_t ws_size,
                              hipStream_t stream) {
  const float* text  = (const float*)d_in[0];
  const float* span  = (const float*)d_in[1];
  const float* img   = (const float*)d_in[2];
  const float* tmask = (const float*)d_in[3];
  const float* smask = (const float*)d_in[4];
  const float* imask = (const float*)d_in[5];
  const float* W1    = (const float*)d_in[6];
  const float* b1    = (const float*)d_in[7];
  const float* W2    = (const float*)d_in[8];
  const float* b2    = (const float*)d_in[9];
  const float* W3    = (const float*)d_in[10];
  const float* b3    = (const float*)d_in[11];

  float* out     = (float*)d_out;
  float* outLoss = out;
  float* outG    = out + 1;
  float* outT    = out + 1 + (size_t)B_ * NS * LI;

  // ---- workspace layout (all 16B aligned) ----
  char* w = (char*)d_ws;
  float*    dotTI = (float*)w;            w += (size_t)(B_*NT) * (B_*LI) * 4;   // 9.4 MB
  float*    S     = (float*)w;            w += 1024 * 4;
  float*    AB1   = (float*)w;            w += (size_t)1536 * 2048 * 4;         // 12.6 MB
  _Float16* h1    = (_Float16*)w;         w += (size_t)ROWS * 1024 * 2;         // 74 MB
  _Float16* P     = (_Float16*)w;         w += (size_t)CHUNK * 1024 * 2;        // 24.6 MB
  _Float16* textH = (_Float16*)w;         w += (size_t)2048 * 1024 * 2;
  _Float16* spanH = (_Float16*)w;         w += (size_t)1536 * 1024 * 2;
  _Float16* imgH  = (_Float16*)w;         w += (size_t)1152 * 1024 * 2;
  _Float16* W1abT = (_Float16*)w;         w += (size_t)2048 * 1024 * 2;
  _Float16* W1cT  = (_Float16*)w;         w += (size_t)1024 * 1024 * 2;
  _Float16* W2T   = (_Float16*)w;         w += (size_t)1024 * 1024 * 2;
  int*      idxF  = (int*)w;              w += ROWS * 4;
  int*      idxS  = (int*)w;              w += ROWS * 4;
  (void)ws_size; (void)in_sizes; (void)n_in; (void)out_size;

  // ---- prep: conversions / transposes / indices ----
  cvt_f16<<<(2048 * 128 + 255) / 256, 256, 0, stream>>>(text, textH, 2048LL * 128);
  cvt_f16<<<(1536 * 128 + 255) / 256, 256, 0, stream>>>(span, spanH, 1536LL * 128);
  cvt_f16<<<(1152 * 128 + 255) / 256, 256, 0, stream>>>(img, imgH, 1152LL * 128);
  transpose_cvt<<<dim3(32, 32), 256, 0, stream>>>(W1, W1abT);                      // W1a^T
  transpose_cvt<<<dim3(32, 32), 256, 0, stream>>>(W1 + 1024 * 1024, W1abT + 1024 * 1024); // W1b^T
  transpose_cvt<<<dim3(32, 32), 256, 0, stream>>>(W1 + 2048 * 1024, W1cT);         // W1c^T
  transpose_cvt<<<dim3(32, 32), 256, 0, stream>>>(W2, W2T);
  idx_init<<<(ROWS + 255) / 256, 256, 0, stream>>>(idxF, idxS);

  // ---- 1) dotTI = text @ img^T -> S -> loss ----
  mfma_gemm<0><<<dim3((B_*LI) / 128, (B_*NT) / 128), 256, 0, stream>>>(
      textH, imgH, dotTI, nullptr, nullptr, nullptr, nullptr, nullptr,
      nullptr, nullptr, B_ * LI, D_, 0);
  sent_kernel<<<dim3(B_, B_), 64, 0, stream>>>(dotTI, tmask, imask, S);
  loss_kernel<<<1, 64, 0, stream>>>(S, outLoss);

  // ---- 2) grounding (f32, exact) ----
  grounding_kernel<<<B_, 256, 0, stream>>>(span, img, smask, imask, outG);

  // ---- 3) pairwise MLP ----
  // AB1 = span @ [W1a | W1b]  (f32 out, 1536 x 2048)
  mfma_gemm<0><<<dim3(2048 / 128, 1536 / 128), 256, 0, stream>>>(
      spanH, W1abT, AB1, nullptr, nullptr, nullptr, nullptr, nullptr,
      nullptr, nullptr, 2048, D_, 0);

  // h1 = relu(P @ W1c + A1 + B1 + b1), in 3 chunks
  for (int cs = 0; cs < ROWS; cs += CHUNK) {
    build_p<<<(CHUNK * 128 + 255) / 256, 256, 0, stream>>>(span, idxF, idxS, P, cs, CHUNK);
    mfma_gemm<1><<<dim3(1024 / 128, CHUNK / 128), 256, 0, stream>>>(
        P, W1cT, nullptr, h1, nullptr, AB1, b1, nullptr, idxF, idxS, 1024, D_, cs);
  }

  // scores = relu(h1 @ W2 + b2) . W3 + b3
  init_scores<<<(ROWS + 255) / 256, 256, 0, stream>>>(outT, b3);
  mfma_gemm<2><<<dim3(1024 / 128, ROWS / 128), 256, 0, stream>>>(
      h1, W2T, nullptr, nullptr, outT, nullptr, b2, W3, nullptr, nullptr, 1024, H_, 0);
}

// Round 3
// 385.921 us; speedup vs baseline: 8.7786x; 1.5536x over previous
//
#include <hip/hip_runtime.h>
#include <math.h>
#include <stdint.h>

#define B_    32
#define NT    64
#define NS    48
#define LI    36
#define D_    1024
#define H_    1024
#define NPAIR 1128            // 48*47/2
#define ROWS  (B_*NPAIR)      // 36096 = 282*128
#define NEGV  -9.0e9f

typedef _Float16 half8 __attribute__((ext_vector_type(8)));
typedef float floatx4 __attribute__((ext_vector_type(4)));
typedef __attribute__((address_space(3))) uint32_t lds_u32;
typedef __attribute__((address_space(1))) const uint32_t glb_u32;

// ---------------------------------------------------------------------------
// Templated MFMA GEMM: C[M,N] = A[M,K] @ Bt[N,K]^T, f16 in, f32 acc.
// 128x128 tile, BK=32, 4 waves, 16x16x32_f16 (m97 structure).
// EPI 0: store f32 C.
// EPI 2: scores += sum_c relu(C + b2[c]) * W3[c]  (atomicAdd per row)
// ---------------------------------------------------------------------------
template<int EPI>
__global__ __launch_bounds__(256) void mfma_gemm(
    const _Float16* __restrict__ A, const _Float16* __restrict__ Bt,
    float* __restrict__ Cf, float* __restrict__ scores,
    const float* __restrict__ bias, const float* __restrict__ W3,
    int N, int K, int rowStart) {
  __shared__ __align__(16) _Float16 sA[128 * 32];
  __shared__ __align__(16) _Float16 sB[128 * 32];
  __shared__ float sRed[128][2];
  const int tid = threadIdx.x;
  const int lane = tid & 63;
  const int wave = tid >> 6;
  const int wr = wave >> 1, wc = wave & 1;
  const int l15 = lane & 15, l16 = lane >> 4;
  const int rowBase = blockIdx.y * 128, colBase = blockIdx.x * 128;

  const int stRow = tid >> 2;            // 0..63
  const int stCol = (tid & 3) << 3;      // halves: 0,8,16,24
  const _Float16* gA = A + (size_t)(rowBase + stRow) * K + stCol;
  const _Float16* gB = Bt + (size_t)(colBase + stRow) * K + stCol;
  _Float16* lA = sA + tid * 8;
  _Float16* lB = sB + tid * 8;

  floatx4 acc[4][4] = {};
  for (int k0 = 0; k0 < K; k0 += 32) {
    __builtin_amdgcn_global_load_lds((glb_u32*)(gA + k0),           (lds_u32*)lA,             16, 0, 0);
    __builtin_amdgcn_global_load_lds((glb_u32*)(gA + 64 * K + k0),  (lds_u32*)(lA + 64 * 32), 16, 0, 0);
    __builtin_amdgcn_global_load_lds((glb_u32*)(gB + k0),           (lds_u32*)lB,             16, 0, 0);
    __builtin_amdgcn_global_load_lds((glb_u32*)(gB + 64 * K + k0),  (lds_u32*)(lB + 64 * 32), 16, 0, 0);
    __syncthreads();
    half8 aF[4], bF[4];
#pragma unroll
    for (int i = 0; i < 4; ++i)
      aF[i] = *(const half8*)&sA[(wr * 64 + i * 16 + l15) * 32 + l16 * 8];
#pragma unroll
    for (int j = 0; j < 4; ++j)
      bF[j] = *(const half8*)&sB[(wc * 64 + j * 16 + l15) * 32 + l16 * 8];
#pragma unroll
    for (int i = 0; i < 4; ++i)
#pragma unroll
      for (int j = 0; j < 4; ++j)
        acc[i][j] = __builtin_amdgcn_mfma_f32_16x16x32_f16(aF[i], bF[j], acc[i][j], 0, 0, 0);
    __syncthreads();
  }

  if (EPI == 0) {
#pragma unroll
    for (int i = 0; i < 4; ++i)
#pragma unroll
      for (int q = 0; q < 4; ++q) {
        int r = rowBase + wr * 64 + i * 16 + l16 * 4 + q;
#pragma unroll
        for (int j = 0; j < 4; ++j) {
          int c = colBase + wc * 64 + j * 16 + l15;
          Cf[(size_t)r * N + c] = acc[i][j][q];
        }
      }
  } else {
    float bv[4], wv[4];
#pragma unroll
    for (int j = 0; j < 4; ++j) {
      int c = colBase + wc * 64 + j * 16 + l15;
      bv[j] = bias[c];
      wv[j] = W3[c];
    }
#pragma unroll
    for (int i = 0; i < 4; ++i)
#pragma unroll
      for (int q = 0; q < 4; ++q) {
        float s = 0.f;
#pragma unroll
        for (int j = 0; j < 4; ++j) s += fmaxf(acc[i][j][q] + bv[j], 0.f) * wv[j];
        s += __shfl_xor(s, 1); s += __shfl_xor(s, 2);
        s += __shfl_xor(s, 4); s += __shfl_xor(s, 8);
        if (l15 == 0) sRed[wr * 64 + i * 16 + l16 * 4 + q][wc] = s;
      }
    __syncthreads();
    if (tid < 128)
      atomicAdd(&scores[rowStart + rowBase + tid], sRed[tid][0] + sRed[tid][1]);
  }
}

// ---------------------------------------------------------------------------
// Fused GEMM1: h1[r] = relu( (spanH[idxF[r]] .* spanH[idxS[r]]) @ W1c
//                             + A1[idxF[r]] + B1[idxS[r]] + b1 ), f16 out.
// A-tile built in-register (gathered pair product), B via global_load_lds.
// ---------------------------------------------------------------------------
__global__ __launch_bounds__(256) void gemm1_fused(
    const _Float16* __restrict__ spanH, const _Float16* __restrict__ W1cT,
    const float* __restrict__ AB1, const float* __restrict__ b1,
    _Float16* __restrict__ h1out,
    const int* __restrict__ idxF, const int* __restrict__ idxS) {
  __shared__ __align__(16) _Float16 sA[128 * 32];
  __shared__ __align__(16) _Float16 sB[128 * 32];
  __shared__ int sIF[128], sIS[128];
  const int tid = threadIdx.x;
  const int lane = tid & 63;
  const int wave = tid >> 6;
  const int wr = wave >> 1, wc = wave & 1;
  const int l15 = lane & 15, l16 = lane >> 4;
  const int rowBase = blockIdx.y * 128, colBase = blockIdx.x * 128;

  if (tid < 128) {
    int rg = rowBase + tid;
    sIF[tid] = idxF[rg];
    sIS[tid] = idxS[rg];
  }
  __syncthreads();

  const int stRow = tid >> 2;            // 0..63
  const int stCol = (tid & 3) << 3;      // halves: 0,8,16,24
  const _Float16* gB = W1cT + (size_t)(colBase + stRow) * D_ + stCol;
  _Float16* lB = sB + tid * 8;
  const size_t pf0 = (size_t)sIF[stRow] * D_;
  const size_t ps0 = (size_t)sIS[stRow] * D_;
  const size_t pf1 = (size_t)sIF[stRow + 64] * D_;
  const size_t ps1 = (size_t)sIS[stRow + 64] * D_;

  floatx4 acc[4][4] = {};
  for (int k0 = 0; k0 < D_; k0 += 32) {
    __builtin_amdgcn_global_load_lds((glb_u32*)(gB + k0),           (lds_u32*)lB,             16, 0, 0);
    __builtin_amdgcn_global_load_lds((glb_u32*)(gB + 64 * D_ + k0), (lds_u32*)(lB + 64 * 32), 16, 0, 0);
    half8 f0 = *(const half8*)(spanH + pf0 + k0 + stCol);
    half8 s0 = *(const half8*)(spanH + ps0 + k0 + stCol);
    half8 f1 = *(const half8*)(spanH + pf1 + k0 + stCol);
    half8 s1 = *(const half8*)(spanH + ps1 + k0 + stCol);
    *(half8*)(sA + stRow * 32 + stCol) = f0 * s0;
    *(half8*)(sA + (stRow + 64) * 32 + stCol) = f1 * s1;
    __syncthreads();
    half8 aF[4], bF[4];
#pragma unroll
    for (int i = 0; i < 4; ++i)
      aF[i] = *(const half8*)&sA[(wr * 64 + i * 16 + l15) * 32 + l16 * 8];
#pragma unroll
    for (int j = 0; j < 4; ++j)
      bF[j] = *(const half8*)&sB[(wc * 64 + j * 16 + l15) * 32 + l16 * 8];
#pragma unroll
    for (int i = 0; i < 4; ++i)
#pragma unroll
      for (int j = 0; j < 4; ++j)
        acc[i][j] = __builtin_amdgcn_mfma_f32_16x16x32_f16(aF[i], bF[j], acc[i][j], 0, 0, 0);
    __syncthreads();
  }

  int cols[4]; float bv[4];
#pragma unroll
  for (int j = 0; j < 4; ++j) {
    cols[j] = colBase + wc * 64 + j * 16 + l15;
    bv[j] = b1[cols[j]];
  }
#pragma unroll
  for (int i = 0; i < 4; ++i)
#pragma unroll
    for (int q = 0; q < 4; ++q) {
      int rL = wr * 64 + i * 16 + l16 * 4 + q;
      int rG = rowBase + rL;
      const float* ap = AB1 + (size_t)sIF[rL] * 2048;
      const float* bp = AB1 + (size_t)sIS[rL] * 2048 + 1024;
#pragma unroll
      for (int j = 0; j < 4; ++j) {
        int c = cols[j];
        float v = acc[i][j][q] + ap[c] + bp[c] + bv[j];
        h1out[(size_t)rG * 1024 + c] = (_Float16)fmaxf(v, 0.f);
      }
    }
}

// f32 -> f16 copy (n8 = elems/8)
__global__ __launch_bounds__(256) void cvt_f16(
    const float* __restrict__ in, _Float16* __restrict__ out, long long n8) {
  long long i = (long long)blockIdx.x * 256 + threadIdx.x;
  if (i >= n8) return;
  const float4* p = (const float4*)in + i * 2;
  float4 a = p[0], b = p[1];
  half8 h;
  h[0] = (_Float16)a.x; h[1] = (_Float16)a.y; h[2] = (_Float16)a.z; h[3] = (_Float16)a.w;
  h[4] = (_Float16)b.x; h[5] = (_Float16)b.y; h[6] = (_Float16)b.z; h[7] = (_Float16)b.w;
  *(half8*)(out + i * 8) = h;
}

// out[n][k] = (f16) in[k][n], 1024x1024
__global__ __launch_bounds__(256) void transpose_cvt(
    const float* __restrict__ in, _Float16* __restrict__ out) {
  __shared__ float t[32][33];
  const int tx = threadIdx.x & 31, ty = threadIdx.x >> 5;
  const int k0 = blockIdx.y * 32, n0 = blockIdx.x * 32;
#pragma unroll
  for (int q = 0; q < 4; ++q)
    t[ty + q * 8][tx] = in[(size_t)(k0 + ty + q * 8) * 1024 + n0 + tx];
  __syncthreads();
#pragma unroll
  for (int q = 0; q < 4; ++q)
    out[(size_t)(n0 + ty + q * 8) * 1024 + k0 + tx] = (_Float16)t[tx][ty + q * 8];
}

__global__ __launch_bounds__(256) void idx_init(int* __restrict__ idxF, int* __restrict__ idxS) {
  int r = blockIdx.x * 256 + threadIdx.x;
  if (r >= ROWS) return;
  int bb = r / NPAIR, p = r - bb * NPAIR;
  int cum = 0, f = 0;
  while (true) { int cnt = NS - 1 - f; if (p < cum + cnt) break; cum += cnt; ++f; }
  idxF[r] = bb * NS + f;
  idxS[r] = bb * NS + f + 1 + (p - cum);
}

__global__ void init_scores(float* __restrict__ scores, const float* __restrict__ b3) {
  int idx = blockIdx.x * 256 + threadIdx.x;
  if (idx < ROWS) scores[idx] = b3[0];
}

// grounding[b,n,l] = mask ? dotSI[b*48+n][b*36+l] : NEG
__global__ __launch_bounds__(256) void extract_grounding(
    const float* __restrict__ dotSI, const float* __restrict__ smask,
    const float* __restrict__ imask, float* __restrict__ outg) {
  int idx = blockIdx.x * 256 + threadIdx.x;
  if (idx >= B_ * NS * LI) return;
  int b = idx / (NS * LI);
  int rem = idx - b * (NS * LI);
  int n = rem / LI, l = rem - n * LI;
  float v = dotSI[(size_t)(b * NS + n) * (B_ * LI) + b * LI + l];
  outg[idx] = (smask[b * NS + n] * imask[b * LI + l] != 0.f) ? v : NEGV;
}

// ---------------------------------------------------------------------------
// Sentence scores S[i,j] (exp(NEG)==0 in f32 -> exact masked softmax)
// ---------------------------------------------------------------------------
__global__ __launch_bounds__(64) void sent_kernel(
    const float* __restrict__ dotTI, const float* __restrict__ tmask,
    const float* __restrict__ imask, float* __restrict__ S) {
  const int i = blockIdx.y, j = blockIdx.x, t = threadIdx.x;
  __shared__ float red1[64], red2[64];
  const int stride = B_ * LI;
  float e1 = 0.f;
  {
    float tm = tmask[i * NT + t];
    if (tm != 0.f) {
      const float* row = dotTI + (size_t)(i * NT + t) * stride + j * LI;
      float m = -INFINITY;
      for (int l = 0; l < LI; ++l) if (imask[j * LI + l] != 0.f) m = fmaxf(m, row[l]);
      float z = 0.f, w = 0.f;
      for (int l = 0; l < LI; ++l) if (imask[j * LI + l] != 0.f) {
        float d = row[l], p = expf(d - m);
        z += p; w += p * d;
      }
      e1 = w / z;
    }
  }
  red1[t] = e1;
  float e2 = 0.f;
  if (t < LI) {
    float im = imask[j * LI + t];
    if (im != 0.f) {
      const float* col = dotTI + (size_t)(i * NT) * stride + j * LI + t;
      float m = -INFINITY;
      for (int n = 0; n < NT; ++n) if (tmask[i * NT + n] != 0.f) m = fmaxf(m, col[(size_t)n * stride]);
      float z = 0.f, w = 0.f;
      for (int n = 0; n < NT; ++n) if (tmask[i * NT + n] != 0.f) {
        float d = col[(size_t)n * stride], p = expf(d - m);
        z += p; w += p * d;
      }
      e2 = w / z;
    }
  }
  red2[t] = e2;
  __syncthreads();
  if (t == 0) {
    float s1 = 0.f, s2 = 0.f, cn = 0.f, cl = 0.f;
    for (int n = 0; n < NT; ++n) { s1 += red1[n]; cn += tmask[i * NT + n]; }
    for (int l = 0; l < LI; ++l) { s2 += red2[l]; cl += imask[j * LI + l]; }
    S[i * B_ + j] = s1 / cn + s2 / cl;
  }
}

__global__ __launch_bounds__(64) void loss_kernel(
    const float* __restrict__ S, float* __restrict__ out) {
  __shared__ float sS[B_][B_ + 1];
  __shared__ float acc[B_];
  const int t = threadIdx.x;
  for (int e = t; e < B_ * B_; e += 64) sS[e / B_][e % B_] = S[e];
  __syncthreads();
  if (t < B_) {
    float m = -INFINITY;
    for (int j = 0; j < B_; ++j) m = fmaxf(m, sS[t][j]);
    float z = 0.f;
    for (int j = 0; j < B_; ++j) z += expf(sS[t][j] - m);
    float lr = m + logf(z);
    float m2 = -INFINITY;
    for (int i = 0; i < B_; ++i) m2 = fmaxf(m2, sS[i][t]);
    float z2 = 0.f;
    for (int i = 0; i < B_; ++i) z2 += expf(sS[i][t] - m2);
    float lc = m2 + logf(z2);
    acc[t] = 2.f * sS[t][t] - lr - lc;
  }
  __syncthreads();
  if (t == 0) {
    float s = 0.f;
    for (int i = 0; i < B_; ++i) s += acc[i];
    out[0] = -s / (float)B_;
  }
}

extern "C" void kernel_launch(void* const* d_in, const int* in_sizes, int n_in,
                              void* d_out, int out_size, void* d_ws, size_t ws_size,
                              hipStream_t stream) {
  const float* text  = (const float*)d_in[0];
  const float* span  = (const float*)d_in[1];
  const float* img   = (const float*)d_in[2];
  const float* tmask = (const float*)d_in[3];
  const float* smask = (const float*)d_in[4];
  const float* imask = (const float*)d_in[5];
  const float* W1    = (const float*)d_in[6];
  const float* b1    = (const float*)d_in[7];
  const float* W2    = (const float*)d_in[8];
  const float* b2    = (const float*)d_in[9];
  const float* W3    = (const float*)d_in[10];
  const float* b3    = (const float*)d_in[11];

  float* out     = (float*)d_out;
  float* outLoss = out;
  float* outG    = out + 1;
  float* outT    = out + 1 + (size_t)B_ * NS * LI;

  // ---- workspace layout (all 16B aligned) ----
  char* w = (char*)d_ws;
  float*    dotTI = (float*)w;            w += (size_t)(B_*NT) * (B_*LI) * 4;   // 9.4 MB
  float*    dotSI = (float*)w;            w += (size_t)(B_*NS) * (B_*LI) * 4;   // 7.1 MB
  float*    S     = (float*)w;            w += 1024 * 4;
  float*    AB1   = (float*)w;            w += (size_t)1536 * 2048 * 4;         // 12.6 MB
  _Float16* h1    = (_Float16*)w;         w += (size_t)ROWS * 1024 * 2;         // 74 MB
  _Float16* textH = (_Float16*)w;         w += (size_t)2048 * 1024 * 2;
  _Float16* spanH = (_Float16*)w;         w += (size_t)1536 * 1024 * 2;
  _Float16* imgH  = (_Float16*)w;         w += (size_t)1152 * 1024 * 2;
  _Float16* W1abT = (_Float16*)w;         w += (size_t)2048 * 1024 * 2;
  _Float16* W1cT  = (_Float16*)w;         w += (size_t)1024 * 1024 * 2;
  _Float16* W2T   = (_Float16*)w;         w += (size_t)1024 * 1024 * 2;
  int*      idxF  = (int*)w;              w += ROWS * 4;
  int*      idxS  = (int*)w;              w += ROWS * 4;
  (void)ws_size; (void)in_sizes; (void)n_in; (void)out_size;

  // ---- prep: conversions / transposes / indices ----
  cvt_f16<<<(2048 * 128 + 255) / 256, 256, 0, stream>>>(text, textH, 2048LL * 128);
  cvt_f16<<<(1536 * 128 + 255) / 256, 256, 0, stream>>>(span, spanH, 1536LL * 128);
  cvt_f16<<<(1152 * 128 + 255) / 256, 256, 0, stream>>>(img, imgH, 1152LL * 128);
  transpose_cvt<<<dim3(32, 32), 256, 0, stream>>>(W1, W1abT);                      // W1a^T
  transpose_cvt<<<dim3(32, 32), 256, 0, stream>>>(W1 + 1024 * 1024, W1abT + 1024 * 1024); // W1b^T
  transpose_cvt<<<dim3(32, 32), 256, 0, stream>>>(W1 + 2048 * 1024, W1cT);         // W1c^T
  transpose_cvt<<<dim3(32, 32), 256, 0, stream>>>(W2, W2T);
  idx_init<<<(ROWS + 255) / 256, 256, 0, stream>>>(idxF, idxS);

  // ---- 1) dotTI = text @ img^T -> S -> loss ----
  mfma_gemm<0><<<dim3((B_*LI) / 128, (B_*NT) / 128), 256, 0, stream>>>(
      textH, imgH, dotTI, nullptr, nullptr, nullptr, B_ * LI, D_, 0);
  sent_kernel<<<dim3(B_, B_), 64, 0, stream>>>(dotTI, tmask, imask, S);
  loss_kernel<<<1, 64, 0, stream>>>(S, outLoss);

  // ---- 2) grounding via full span-image GEMM + diagonal extract ----
  mfma_gemm<0><<<dim3((B_*LI) / 128, (B_*NS) / 128), 256, 0, stream>>>(
      spanH, imgH, dotSI, nullptr, nullptr, nullptr, B_ * LI, D_, 0);
  extract_grounding<<<(B_*NS*LI + 255) / 256, 256, 0, stream>>>(dotSI, smask, imask, outG);

  // ---- 3) pairwise MLP ----
  // AB1 = span @ [W1a | W1b]  (f32 out, 1536 x 2048)
  mfma_gemm<0><<<dim3(2048 / 128, 1536 / 128), 256, 0, stream>>>(
      spanH, W1abT, AB1, nullptr, nullptr, nullptr, 2048, D_, 0);

  // h1 = relu((span_f .* span_s) @ W1c + A1 + B1 + b1), fused pair product
  gemm1_fused<<<dim3(1024 / 128, ROWS / 128), 256, 0, stream>>>(
      spanH, W1cT, AB1, b1, h1, idxF, idxS);

  // scores = relu(h1 @ W2 + b2) . W3 + b3
  init_scores<<<(ROWS + 255) / 256, 256, 0, stream>>>(outT, b3);
  mfma_gemm<2><<<dim3(1024 / 128, ROWS / 128), 256, 0, stream>>>(
      h1, W2T, nullptr, outT, b2, W3, 1024, H_, 0);
}

// Round 4
// 362.774 us; speedup vs baseline: 9.3387x; 1.0638x over previous
//
#include <hip/hip_runtime.h>
#include <math.h>
#include <stdint.h>

#define B_    32
#define NT    64
#define NS    48
#define LI    36
#define D_    1024
#define H_    1024
#define NPAIR 1128            // 48*47/2
#define ROWS  (B_*NPAIR)      // 36096 = 282*128
#define NEGV  -9.0e9f
#define NROWT 282             // row tiles of 128
#define CPX   36              // ceil(282/8) row tiles per XCD

typedef _Float16 half8 __attribute__((ext_vector_type(8)));
typedef float floatx4 __attribute__((ext_vector_type(4)));
typedef __attribute__((address_space(3))) uint32_t lds_u32;
typedef __attribute__((address_space(1))) const uint32_t glb_u32;

#define GLOAD16(src, dst) __builtin_amdgcn_global_load_lds((glb_u32*)(src), (lds_u32*)(dst), 16, 0, 0)

// ---------------------------------------------------------------------------
// MFMA GEMM: C[M,N] = A[M,K] @ Bt[N,K]^T, f16 in, f32 acc.
// 128x128 tile, BK=64 (two 32-K subtiles, one barrier pair), 4 waves.
// REMAP=1: grid.x = 2304 linear, XCD-contiguous row-strip chunks.
// EPI 0: store f32 C.   EPI 2: scores += sum_c relu(C+b2[c])*W3[c]
// ---------------------------------------------------------------------------
template<int EPI, int REMAP>
__global__ __launch_bounds__(256) void mfma_gemm(
    const _Float16* __restrict__ A, const _Float16* __restrict__ Bt,
    float* __restrict__ Cf, float* __restrict__ scores,
    const float* __restrict__ bias, const float* __restrict__ W3,
    int N, int K) {
  __shared__ __align__(16) _Float16 sA[8192];   // [2 sub][128][32]
  __shared__ __align__(16) _Float16 sB[8192];
  __shared__ float sRed[128][2];
  int rowT, colT;
  if (REMAP) {
    int bid = blockIdx.x;
    int x = bid & 7, ord = bid >> 3;
    rowT = x * CPX + (ord >> 3);
    colT = ord & 7;
    if (rowT >= NROWT) return;
  } else {
    rowT = blockIdx.y; colT = blockIdx.x;
  }
  const int rowBase = rowT * 128, colBase = colT * 128;
  const int tid = threadIdx.x;
  const int lane = tid & 63;
  const int wave = tid >> 6;
  const int wr = wave >> 1, wc = wave & 1;
  const int l15 = lane & 15, l16 = lane >> 4;

  const int sRow = tid >> 2;            // 0..63
  const int sCol = (tid & 3) << 3;      // 0,8,16,24
  const _Float16* gA = A + (size_t)(rowBase + sRow) * K + sCol;
  const _Float16* gB = Bt + (size_t)(colBase + sRow) * K + sCol;
  _Float16* lA = sA + tid * 8;
  _Float16* lB = sB + tid * 8;

  floatx4 acc[4][4] = {};
  for (int k0 = 0; k0 < K; k0 += 64) {
    GLOAD16(gA + k0,              lA);
    GLOAD16(gA + 64 * K + k0,     lA + 2048);
    GLOAD16(gA + k0 + 32,         lA + 4096);
    GLOAD16(gA + 64 * K + k0 + 32,lA + 6144);
    GLOAD16(gB + k0,              lB);
    GLOAD16(gB + 64 * K + k0,     lB + 2048);
    GLOAD16(gB + k0 + 32,         lB + 4096);
    GLOAD16(gB + 64 * K + k0 + 32,lB + 6144);
    __syncthreads();
#pragma unroll
    for (int h = 0; h < 2; ++h) {
      const int hb = h * 4096;
      half8 aF[4], bF[4];
#pragma unroll
      for (int i = 0; i < 4; ++i)
        aF[i] = *(const half8*)&sA[hb + (wr * 64 + i * 16 + l15) * 32 + l16 * 8];
#pragma unroll
      for (int j = 0; j < 4; ++j)
        bF[j] = *(const half8*)&sB[hb + (wc * 64 + j * 16 + l15) * 32 + l16 * 8];
#pragma unroll
      for (int i = 0; i < 4; ++i)
#pragma unroll
        for (int j = 0; j < 4; ++j)
          acc[i][j] = __builtin_amdgcn_mfma_f32_16x16x32_f16(aF[i], bF[j], acc[i][j], 0, 0, 0);
    }
    __syncthreads();
  }

  if (EPI == 0) {
#pragma unroll
    for (int i = 0; i < 4; ++i)
#pragma unroll
      for (int q = 0; q < 4; ++q) {
        int r = rowBase + wr * 64 + i * 16 + l16 * 4 + q;
#pragma unroll
        for (int j = 0; j < 4; ++j) {
          int c = colBase + wc * 64 + j * 16 + l15;
          Cf[(size_t)r * N + c] = acc[i][j][q];
        }
      }
  } else {
    float bv[4], wv[4];
#pragma unroll
    for (int j = 0; j < 4; ++j) {
      int c = colBase + wc * 64 + j * 16 + l15;
      bv[j] = bias[c];
      wv[j] = W3[c];
    }
#pragma unroll
    for (int i = 0; i < 4; ++i)
#pragma unroll
      for (int q = 0; q < 4; ++q) {
        float s = 0.f;
#pragma unroll
        for (int j = 0; j < 4; ++j) s += fmaxf(acc[i][j][q] + bv[j], 0.f) * wv[j];
        s += __shfl_xor(s, 1); s += __shfl_xor(s, 2);
        s += __shfl_xor(s, 4); s += __shfl_xor(s, 8);
        if (l15 == 0) sRed[wr * 64 + i * 16 + l16 * 4 + q][wc] = s;
      }
    __syncthreads();
    if (tid < 128)
      atomicAdd(&scores[rowBase + tid], sRed[tid][0] + sRed[tid][1]);
  }
}

// ---------------------------------------------------------------------------
// Fused GEMM1: h1[r] = relu( (spanH[idxF[r]] .* spanH[idxS[r]]) @ W1c
//                             + A1[idxF[r]] + B1[idxS[r]] + b1 ), f16 out.
// BK=64 (2 subtiles), XCD-contiguous remap, A built in-register.
// ---------------------------------------------------------------------------
__global__ __launch_bounds__(256) void gemm1_fused(
    const _Float16* __restrict__ spanH, const _Float16* __restrict__ W1cT,
    const float* __restrict__ AB1, const float* __restrict__ b1,
    _Float16* __restrict__ h1out,
    const int* __restrict__ idxF, const int* __restrict__ idxS) {
  __shared__ __align__(16) _Float16 sA[8192];
  __shared__ __align__(16) _Float16 sB[8192];
  __shared__ int sIF[128], sIS[128];
  int bid = blockIdx.x;
  int x = bid & 7, ord = bid >> 3;
  int rowT = x * CPX + (ord >> 3);
  int colT = ord & 7;
  if (rowT >= NROWT) return;
  const int rowBase = rowT * 128, colBase = colT * 128;
  const int tid = threadIdx.x;
  const int lane = tid & 63;
  const int wave = tid >> 6;
  const int wr = wave >> 1, wc = wave & 1;
  const int l15 = lane & 15, l16 = lane >> 4;

  if (tid < 128) {
    int rg = rowBase + tid;
    sIF[tid] = idxF[rg];
    sIS[tid] = idxS[rg];
  }
  __syncthreads();

  const int sRow = tid >> 2;            // 0..63
  const int sCol = (tid & 3) << 3;      // 0,8,16,24
  const _Float16* gB = W1cT + (size_t)(colBase + sRow) * D_ + sCol;
  _Float16* lB = sB + tid * 8;
  const _Float16* pf0 = spanH + (size_t)sIF[sRow] * D_ + sCol;
  const _Float16* ps0 = spanH + (size_t)sIS[sRow] * D_ + sCol;
  const _Float16* pf1 = spanH + (size_t)sIF[sRow + 64] * D_ + sCol;
  const _Float16* ps1 = spanH + (size_t)sIS[sRow + 64] * D_ + sCol;

  floatx4 acc[4][4] = {};
  for (int k0 = 0; k0 < D_; k0 += 64) {
    GLOAD16(gB + k0,               lB);
    GLOAD16(gB + 64 * D_ + k0,     lB + 2048);
    GLOAD16(gB + k0 + 32,          lB + 4096);
    GLOAD16(gB + 64 * D_ + k0 + 32,lB + 6144);
    half8 f00 = *(const half8*)(pf0 + k0);
    half8 s00 = *(const half8*)(ps0 + k0);
    half8 f10 = *(const half8*)(pf1 + k0);
    half8 s10 = *(const half8*)(ps1 + k0);
    half8 f01 = *(const half8*)(pf0 + k0 + 32);
    half8 s01 = *(const half8*)(ps0 + k0 + 32);
    half8 f11 = *(const half8*)(pf1 + k0 + 32);
    half8 s11 = *(const half8*)(ps1 + k0 + 32);
    *(half8*)(sA + tid * 8)        = f00 * s00;
    *(half8*)(sA + 2048 + tid * 8) = f10 * s10;
    *(half8*)(sA + 4096 + tid * 8) = f01 * s01;
    *(half8*)(sA + 6144 + tid * 8) = f11 * s11;
    __syncthreads();
#pragma unroll
    for (int h = 0; h < 2; ++h) {
      const int hb = h * 4096;
      half8 aF[4], bF[4];
#pragma unroll
      for (int i = 0; i < 4; ++i)
        aF[i] = *(const half8*)&sA[hb + (wr * 64 + i * 16 + l15) * 32 + l16 * 8];
#pragma unroll
      for (int j = 0; j < 4; ++j)
        bF[j] = *(const half8*)&sB[hb + (wc * 64 + j * 16 + l15) * 32 + l16 * 8];
#pragma unroll
      for (int i = 0; i < 4; ++i)
#pragma unroll
        for (int j = 0; j < 4; ++j)
          acc[i][j] = __builtin_amdgcn_mfma_f32_16x16x32_f16(aF[i], bF[j], acc[i][j], 0, 0, 0);
    }
    __syncthreads();
  }

  int cols[4]; float bv[4];
#pragma unroll
  for (int j = 0; j < 4; ++j) {
    cols[j] = colBase + wc * 64 + j * 16 + l15;
    bv[j] = b1[cols[j]];
  }
#pragma unroll
  for (int i = 0; i < 4; ++i)
#pragma unroll
    for (int q = 0; q < 4; ++q) {
      int rL = wr * 64 + i * 16 + l16 * 4 + q;
      int rG = rowBase + rL;
      const float* ap = AB1 + (size_t)sIF[rL] * 2048;
      const float* bp = AB1 + (size_t)sIS[rL] * 2048 + 1024;
#pragma unroll
      for (int j = 0; j < 4; ++j) {
        int c = cols[j];
        float v = acc[i][j][q] + ap[c] + bp[c] + bv[j];
        h1out[(size_t)rG * 1024 + c] = (_Float16)fmaxf(v, 0.f);
      }
    }
}

// f32 -> f16 copy (n8 = elems/8)
__global__ __launch_bounds__(256) void cvt_f16(
    const float* __restrict__ in, _Float16* __restrict__ out, long long n8) {
  long long i = (long long)blockIdx.x * 256 + threadIdx.x;
  if (i >= n8) return;
  const float4* p = (const float4*)in + i * 2;
  float4 a = p[0], b = p[1];
  half8 h;
  h[0] = (_Float16)a.x; h[1] = (_Float16)a.y; h[2] = (_Float16)a.z; h[3] = (_Float16)a.w;
  h[4] = (_Float16)b.x; h[5] = (_Float16)b.y; h[6] = (_Float16)b.z; h[7] = (_Float16)b.w;
  *(half8*)(out + i * 8) = h;
}

// out[n][k] = (f16) in[k][n], 1024x1024
__global__ __launch_bounds__(256) void transpose_cvt(
    const float* __restrict__ in, _Float16* __restrict__ out) {
  __shared__ float t[32][33];
  const int tx = threadIdx.x & 31, ty = threadIdx.x >> 5;
  const int k0 = blockIdx.y * 32, n0 = blockIdx.x * 32;
#pragma unroll
  for (int q = 0; q < 4; ++q)
    t[ty + q * 8][tx] = in[(size_t)(k0 + ty + q * 8) * 1024 + n0 + tx];
  __syncthreads();
#pragma unroll
  for (int q = 0; q < 4; ++q)
    out[(size_t)(n0 + ty + q * 8) * 1024 + k0 + tx] = (_Float16)t[tx][ty + q * 8];
}

__global__ __launch_bounds__(256) void idx_init(int* __restrict__ idxF, int* __restrict__ idxS) {
  int r = blockIdx.x * 256 + threadIdx.x;
  if (r >= ROWS) return;
  int bb = r / NPAIR, p = r - bb * NPAIR;
  int cum = 0, f = 0;
  while (true) { int cnt = NS - 1 - f; if (p < cum + cnt) break; cum += cnt; ++f; }
  idxF[r] = bb * NS + f;
  idxS[r] = bb * NS + f + 1 + (p - cum);
}

__global__ void init_scores(float* __restrict__ scores, const float* __restrict__ b3) {
  int idx = blockIdx.x * 256 + threadIdx.x;
  if (idx < ROWS) scores[idx] = b3[0];
}

// grounding[b,n,l] = mask ? dotSI[b*48+n][b*36+l] : NEG
__global__ __launch_bounds__(256) void extract_grounding(
    const float* __restrict__ dotSI, const float* __restrict__ smask,
    const float* __restrict__ imask, float* __restrict__ outg) {
  int idx = blockIdx.x * 256 + threadIdx.x;
  if (idx >= B_ * NS * LI) return;
  int b = idx / (NS * LI);
  int rem = idx - b * (NS * LI);
  int n = rem / LI, l = rem - n * LI;
  float v = dotSI[(size_t)(b * NS + n) * (B_ * LI) + b * LI + l];
  outg[idx] = (smask[b * NS + n] * imask[b * LI + l] != 0.f) ? v : NEGV;
}

// ---------------------------------------------------------------------------
// Sentence scores S[i,j] (exp(NEG)==0 in f32 -> exact masked softmax)
// ---------------------------------------------------------------------------
__global__ __launch_bounds__(64) void sent_kernel(
    const float* __restrict__ dotTI, const float* __restrict__ tmask,
    const float* __restrict__ imask, float* __restrict__ S) {
  const int i = blockIdx.y, j = blockIdx.x, t = threadIdx.x;
  __shared__ float red1[64], red2[64];
  const int stride = B_ * LI;
  float e1 = 0.f;
  {
    float tm = tmask[i * NT + t];
    if (tm != 0.f) {
      const float* row = dotTI + (size_t)(i * NT + t) * stride + j * LI;
      float m = -INFINITY;
      for (int l = 0; l < LI; ++l) if (imask[j * LI + l] != 0.f) m = fmaxf(m, row[l]);
      float z = 0.f, w = 0.f;
      for (int l = 0; l < LI; ++l) if (imask[j * LI + l] != 0.f) {
        float d = row[l], p = expf(d - m);
        z += p; w += p * d;
      }
      e1 = w / z;
    }
  }
  red1[t] = e1;
  float e2 = 0.f;
  if (t < LI) {
    float im = imask[j * LI + t];
    if (im != 0.f) {
      const float* col = dotTI + (size_t)(i * NT) * stride + j * LI + t;
      float m = -INFINITY;
      for (int n = 0; n < NT; ++n) if (tmask[i * NT + n] != 0.f) m = fmaxf(m, col[(size_t)n * stride]);
      float z = 0.f, w = 0.f;
      for (int n = 0; n < NT; ++n) if (tmask[i * NT + n] != 0.f) {
        float d = col[(size_t)n * stride], p = expf(d - m);
        z += p; w += p * d;
      }
      e2 = w / z;
    }
  }
  red2[t] = e2;
  __syncthreads();
  if (t == 0) {
    float s1 = 0.f, s2 = 0.f, cn = 0.f, cl = 0.f;
    for (int n = 0; n < NT; ++n) { s1 += red1[n]; cn += tmask[i * NT + n]; }
    for (int l = 0; l < LI; ++l) { s2 += red2[l]; cl += imask[j * LI + l]; }
    S[i * B_ + j] = s1 / cn + s2 / cl;
  }
}

__global__ __launch_bounds__(64) void loss_kernel(
    const float* __restrict__ S, float* __restrict__ out) {
  __shared__ float sS[B_][B_ + 1];
  __shared__ float acc[B_];
  const int t = threadIdx.x;
  for (int e = t; e < B_ * B_; e += 64) sS[e / B_][e % B_] = S[e];
  __syncthreads();
  if (t < B_) {
    float m = -INFINITY;
    for (int j = 0; j < B_; ++j) m = fmaxf(m, sS[t][j]);
    float z = 0.f;
    for (int j = 0; j < B_; ++j) z += expf(sS[t][j] - m);
    float lr = m + logf(z);
    float m2 = -INFINITY;
    for (int i = 0; i < B_; ++i) m2 = fmaxf(m2, sS[i][t]);
    float z2 = 0.f;
    for (int i = 0; i < B_; ++i) z2 += expf(sS[i][t] - m2);
    float lc = m2 + logf(z2);
    acc[t] = 2.f * sS[t][t] - lr - lc;
  }
  __syncthreads();
  if (t == 0) {
    float s = 0.f;
    for (int i = 0; i < B_; ++i) s += acc[i];
    out[0] = -s / (float)B_;
  }
}

extern "C" void kernel_launch(void* const* d_in, const int* in_sizes, int n_in,
                              void* d_out, int out_size, void* d_ws, size_t ws_size,
                              hipStream_t stream) {
  const float* text  = (const float*)d_in[0];
  const float* span  = (const float*)d_in[1];
  const float* img   = (const float*)d_in[2];
  const float* tmask = (const float*)d_in[3];
  const float* smask = (const float*)d_in[4];
  const float* imask = (const float*)d_in[5];
  const float* W1    = (const float*)d_in[6];
  const float* b1    = (const float*)d_in[7];
  const float* W2    = (const float*)d_in[8];
  const float* b2    = (const float*)d_in[9];
  const float* W3    = (const float*)d_in[10];
  const float* b3    = (const float*)d_in[11];

  float* out     = (float*)d_out;
  float* outLoss = out;
  float* outG    = out + 1;
  float* outT    = out + 1 + (size_t)B_ * NS * LI;

  // ---- workspace layout (all 16B aligned) ----
  char* w = (char*)d_ws;
  float*    dotTI = (float*)w;            w += (size_t)(B_*NT) * (B_*LI) * 4;   // 9.4 MB
  float*    dotSI = (float*)w;            w += (size_t)(B_*NS) * (B_*LI) * 4;   // 7.1 MB
  float*    S     = (float*)w;            w += 1024 * 4;
  float*    AB1   = (float*)w;            w += (size_t)1536 * 2048 * 4;         // 12.6 MB
  _Float16* h1    = (_Float16*)w;         w += (size_t)ROWS * 1024 * 2;         // 74 MB
  _Float16* textH = (_Float16*)w;         w += (size_t)2048 * 1024 * 2;
  _Float16* spanH = (_Float16*)w;         w += (size_t)1536 * 1024 * 2;
  _Float16* imgH  = (_Float16*)w;         w += (size_t)1152 * 1024 * 2;
  _Float16* W1abT = (_Float16*)w;         w += (size_t)2048 * 1024 * 2;
  _Float16* W1cT  = (_Float16*)w;         w += (size_t)1024 * 1024 * 2;
  _Float16* W2T   = (_Float16*)w;         w += (size_t)1024 * 1024 * 2;
  int*      idxF  = (int*)w;              w += ROWS * 4;
  int*      idxS  = (int*)w;              w += ROWS * 4;
  (void)ws_size; (void)in_sizes; (void)n_in; (void)out_size;

  // ---- prep: conversions / transposes / indices ----
  cvt_f16<<<(2048 * 128 + 255) / 256, 256, 0, stream>>>(text, textH, 2048LL * 128);
  cvt_f16<<<(1536 * 128 + 255) / 256, 256, 0, stream>>>(span, spanH, 1536LL * 128);
  cvt_f16<<<(1152 * 128 + 255) / 256, 256, 0, stream>>>(img, imgH, 1152LL * 128);
  transpose_cvt<<<dim3(32, 32), 256, 0, stream>>>(W1, W1abT);                      // W1a^T
  transpose_cvt<<<dim3(32, 32), 256, 0, stream>>>(W1 + 1024 * 1024, W1abT + 1024 * 1024); // W1b^T
  transpose_cvt<<<dim3(32, 32), 256, 0, stream>>>(W1 + 2048 * 1024, W1cT);         // W1c^T
  transpose_cvt<<<dim3(32, 32), 256, 0, stream>>>(W2, W2T);
  idx_init<<<(ROWS + 255) / 256, 256, 0, stream>>>(idxF, idxS);

  // ---- 1) dotTI = text @ img^T -> S -> loss ----
  mfma_gemm<0, 0><<<dim3((B_*LI) / 128, (B_*NT) / 128), 256, 0, stream>>>(
      textH, imgH, dotTI, nullptr, nullptr, nullptr, B_ * LI, D_);
  sent_kernel<<<dim3(B_, B_), 64, 0, stream>>>(dotTI, tmask, imask, S);
  loss_kernel<<<1, 64, 0, stream>>>(S, outLoss);

  // ---- 2) grounding via full span-image GEMM + diagonal extract ----
  mfma_gemm<0, 0><<<dim3((B_*LI) / 128, (B_*NS) / 128), 256, 0, stream>>>(
      spanH, imgH, dotSI, nullptr, nullptr, nullptr, B_ * LI, D_);
  extract_grounding<<<(B_*NS*LI + 255) / 256, 256, 0, stream>>>(dotSI, smask, imask, outG);

  // ---- 3) pairwise MLP ----
  // AB1 = span @ [W1a | W1b]  (f32 out, 1536 x 2048)
  mfma_gemm<0, 0><<<dim3(2048 / 128, 1536 / 128), 256, 0, stream>>>(
      spanH, W1abT, AB1, nullptr, nullptr, nullptr, 2048, D_);

  // h1 = relu((span_f .* span_s) @ W1c + A1 + B1 + b1), fused pair product
  gemm1_fused<<<8 * CPX * 8, 256, 0, stream>>>(
      spanH, W1cT, AB1, b1, h1, idxF, idxS);

  // scores = relu(h1 @ W2 + b2) . W3 + b3
  init_scores<<<(ROWS + 255) / 256, 256, 0, stream>>>(outT, b3);
  mfma_gemm<2, 1><<<8 * CPX * 8, 256, 0, stream>>>(
      h1, W2T, nullptr, outT, b2, W3, 1024, H_);
}

// Round 5
// 354.112 us; speedup vs baseline: 9.5671x; 1.0245x over previous
//
#include <hip/hip_runtime.h>
#include <math.h>
#include <stdint.h>

#define B_    32
#define NT    64
#define NS    48
#define LI    36
#define D_    1024
#define H_    1024
#define NPAIR 1128            // 48*47/2
#define ROWS  (B_*NPAIR)      // 36096 = 282*128
#define NEGV  -9.0e9f
#define NROWT 282             // row tiles of 128
#define CPX   36              // ceil(282/8) row tiles per XCD

typedef _Float16 half8 __attribute__((ext_vector_type(8)));
typedef float floatx4 __attribute__((ext_vector_type(4)));
typedef __attribute__((address_space(3))) uint32_t lds_u32;
typedef __attribute__((address_space(1))) const uint32_t glb_u32;

#define GLOAD16(src, dst) __builtin_amdgcn_global_load_lds((glb_u32*)(src), (lds_u32*)(dst), 16, 0, 0)

// LDS tile layout: [2 sub][128 rows][4 slots of 8 halves].  Bank-conflict-free
// via slot-XOR swizzle: physical slot = logical slot ^ ((row>>1)&3).
// LDS dest stays LINEAR (global_load_lds constraint); the swizzle is applied
// on the per-lane GLOBAL source column at staging and on the read address.
// Staging source col offset (halves), thread tid -> row=tid>>2, slot=tid&3:
//   swz8(tid) = ((tid&3) ^ ((tid>>3)&3)) << 3
// Read: slot = l16 ^ ((l15>>1)&3)  (row = base + frag*16 + l15; base,frag*16 ≡ 0 mod 32 rows)

// ---------------------------------------------------------------------------
// MFMA GEMM: C[M,N] = A[M,K] @ Bt[N,K]^T, f16 in, f32 acc.
// 128x128 tile, BK=64, 4 waves, 16x16x32_f16 (m97 structure + swizzle).
// REMAP=1: grid.x = 2304 linear, XCD-contiguous row-strip chunks.
// EPI 0: store f32 C.   EPI 2: scores += sum_c relu(C+b2[c])*W3[c]
// ---------------------------------------------------------------------------
template<int EPI, int REMAP>
__global__ __launch_bounds__(256) void mfma_gemm(
    const _Float16* __restrict__ A, const _Float16* __restrict__ Bt,
    float* __restrict__ Cf, float* __restrict__ scores,
    const float* __restrict__ bias, const float* __restrict__ W3,
    int N, int K) {
  __shared__ __align__(16) _Float16 sA[8192];   // [2 sub][128][32]
  __shared__ __align__(16) _Float16 sB[8192];
  __shared__ float sRed[128][2];
  int rowT, colT;
  if (REMAP) {
    int bid = blockIdx.x;
    int x = bid & 7, ord = bid >> 3;
    rowT = x * CPX + (ord >> 3);
    colT = ord & 7;
    if (rowT >= NROWT) return;
  } else {
    rowT = blockIdx.y; colT = blockIdx.x;
  }
  const int rowBase = rowT * 128, colBase = colT * 128;
  const int tid = threadIdx.x;
  const int lane = tid & 63;
  const int wave = tid >> 6;
  const int wr = wave >> 1, wc = wave & 1;
  const int l15 = lane & 15, l16 = lane >> 4;
  const int rsw = (l15 >> 1) & 3;               // read-side swizzle term

  const int sRow = tid >> 2;                    // 0..63
  const int swz8 = (((tid & 3) ^ ((tid >> 3) & 3)) << 3);
  const _Float16* gA = A + (size_t)(rowBase + sRow) * K + swz8;
  const _Float16* gB = Bt + (size_t)(colBase + sRow) * K + swz8;
  _Float16* lA = sA + tid * 8;
  _Float16* lB = sB + tid * 8;

  floatx4 acc[4][4] = {};
  for (int k0 = 0; k0 < K; k0 += 64) {
    GLOAD16(gA + k0,               lA);
    GLOAD16(gA + 64 * K + k0,      lA + 2048);
    GLOAD16(gA + k0 + 32,          lA + 4096);
    GLOAD16(gA + 64 * K + k0 + 32, lA + 6144);
    GLOAD16(gB + k0,               lB);
    GLOAD16(gB + 64 * K + k0,      lB + 2048);
    GLOAD16(gB + k0 + 32,          lB + 4096);
    GLOAD16(gB + 64 * K + k0 + 32, lB + 6144);
    __syncthreads();
#pragma unroll
    for (int h = 0; h < 2; ++h) {
      const int hb = h * 4096;
      half8 aF[4], bF[4];
#pragma unroll
      for (int i = 0; i < 4; ++i)
        aF[i] = *(const half8*)&sA[hb + (wr * 64 + i * 16 + l15) * 32 + ((l16 ^ rsw) << 3)];
#pragma unroll
      for (int j = 0; j < 4; ++j)
        bF[j] = *(const half8*)&sB[hb + (wc * 64 + j * 16 + l15) * 32 + ((l16 ^ rsw) << 3)];
#pragma unroll
      for (int i = 0; i < 4; ++i)
#pragma unroll
        for (int j = 0; j < 4; ++j)
          acc[i][j] = __builtin_amdgcn_mfma_f32_16x16x32_f16(aF[i], bF[j], acc[i][j], 0, 0, 0);
    }
    __syncthreads();
  }

  if (EPI == 0) {
#pragma unroll
    for (int i = 0; i < 4; ++i)
#pragma unroll
      for (int q = 0; q < 4; ++q) {
        int r = rowBase + wr * 64 + i * 16 + l16 * 4 + q;
#pragma unroll
        for (int j = 0; j < 4; ++j) {
          int c = colBase + wc * 64 + j * 16 + l15;
          Cf[(size_t)r * N + c] = acc[i][j][q];
        }
      }
  } else {
    float bv[4], wv[4];
#pragma unroll
    for (int j = 0; j < 4; ++j) {
      int c = colBase + wc * 64 + j * 16 + l15;
      bv[j] = bias[c];
      wv[j] = W3[c];
    }
#pragma unroll
    for (int i = 0; i < 4; ++i)
#pragma unroll
      for (int q = 0; q < 4; ++q) {
        float s = 0.f;
#pragma unroll
        for (int j = 0; j < 4; ++j) s += fmaxf(acc[i][j][q] + bv[j], 0.f) * wv[j];
        s += __shfl_xor(s, 1); s += __shfl_xor(s, 2);
        s += __shfl_xor(s, 4); s += __shfl_xor(s, 8);
        if (l15 == 0) sRed[wr * 64 + i * 16 + l16 * 4 + q][wc] = s;
      }
    __syncthreads();
    if (tid < 128)
      atomicAdd(&scores[rowBase + tid], sRed[tid][0] + sRed[tid][1]);
  }
}

// ---------------------------------------------------------------------------
// Fused GEMM1: h1[r] = relu( (spanH[idxF[r]] .* spanH[idxS[r]]) @ W1c
//                             + A1[idxF[r]] + B1[idxS[r]] + b1 ), f16 out.
// F and S staged as separate LINEAR LDS tiles via gathered global_load_lds
// (per-lane source address); pair product done at fragment-read time.
// BK=64, slot-XOR swizzle, XCD-contiguous remap.
// ---------------------------------------------------------------------------
__global__ __launch_bounds__(256) void gemm1_fused(
    const _Float16* __restrict__ spanH, const _Float16* __restrict__ W1cT,
    const float* __restrict__ AB1, const float* __restrict__ b1,
    _Float16* __restrict__ h1out,
    const int* __restrict__ idxF, const int* __restrict__ idxS) {
  __shared__ __align__(16) _Float16 sF[8192];
  __shared__ __align__(16) _Float16 sS[8192];
  __shared__ __align__(16) _Float16 sB[8192];
  __shared__ int sIF[128], sIS[128];
  int bid = blockIdx.x;
  int x = bid & 7, ord = bid >> 3;
  int rowT = x * CPX + (ord >> 3);
  int colT = ord & 7;
  if (rowT >= NROWT) return;
  const int rowBase = rowT * 128, colBase = colT * 128;
  const int tid = threadIdx.x;
  const int lane = tid & 63;
  const int wave = tid >> 6;
  const int wr = wave >> 1, wc = wave & 1;
  const int l15 = lane & 15, l16 = lane >> 4;
  const int rsw = (l15 >> 1) & 3;

  if (tid < 128) {
    int rg = rowBase + tid;
    sIF[tid] = idxF[rg];
    sIS[tid] = idxS[rg];
  }
  __syncthreads();

  const int sRow = tid >> 2;                    // 0..63
  const int swz8 = (((tid & 3) ^ ((tid >> 3) & 3)) << 3);
  const _Float16* gF0 = spanH + (size_t)sIF[sRow] * D_ + swz8;
  const _Float16* gF1 = spanH + (size_t)sIF[sRow + 64] * D_ + swz8;
  const _Float16* gS0 = spanH + (size_t)sIS[sRow] * D_ + swz8;
  const _Float16* gS1 = spanH + (size_t)sIS[sRow + 64] * D_ + swz8;
  const _Float16* gB  = W1cT + (size_t)(colBase + sRow) * D_ + swz8;
  _Float16* lF = sF + tid * 8;
  _Float16* lS = sS + tid * 8;
  _Float16* lB = sB + tid * 8;

  floatx4 acc[4][4] = {};
  for (int k0 = 0; k0 < D_; k0 += 64) {
    GLOAD16(gF0 + k0,      lF);
    GLOAD16(gF1 + k0,      lF + 2048);
    GLOAD16(gF0 + k0 + 32, lF + 4096);
    GLOAD16(gF1 + k0 + 32, lF + 6144);
    GLOAD16(gS0 + k0,      lS);
    GLOAD16(gS1 + k0,      lS + 2048);
    GLOAD16(gS0 + k0 + 32, lS + 4096);
    GLOAD16(gS1 + k0 + 32, lS + 6144);
    GLOAD16(gB + k0,               lB);
    GLOAD16(gB + 64 * D_ + k0,     lB + 2048);
    GLOAD16(gB + k0 + 32,          lB + 4096);
    GLOAD16(gB + 64 * D_ + k0 + 32,lB + 6144);
    __syncthreads();
#pragma unroll
    for (int h = 0; h < 2; ++h) {
      const int hb = h * 4096;
      half8 aF[4], bF[4];
#pragma unroll
      for (int i = 0; i < 4; ++i) {
        int off = hb + (wr * 64 + i * 16 + l15) * 32 + ((l16 ^ rsw) << 3);
        half8 f = *(const half8*)&sF[off];
        half8 s = *(const half8*)&sS[off];
        aF[i] = f * s;
      }
#pragma unroll
      for (int j = 0; j < 4; ++j)
        bF[j] = *(const half8*)&sB[hb + (wc * 64 + j * 16 + l15) * 32 + ((l16 ^ rsw) << 3)];
#pragma unroll
      for (int i = 0; i < 4; ++i)
#pragma unroll
        for (int j = 0; j < 4; ++j)
          acc[i][j] = __builtin_amdgcn_mfma_f32_16x16x32_f16(aF[i], bF[j], acc[i][j], 0, 0, 0);
    }
    __syncthreads();
  }

  int cols[4]; float bv[4];
#pragma unroll
  for (int j = 0; j < 4; ++j) {
    cols[j] = colBase + wc * 64 + j * 16 + l15;
    bv[j] = b1[cols[j]];
  }
#pragma unroll
  for (int i = 0; i < 4; ++i)
#pragma unroll
    for (int q = 0; q < 4; ++q) {
      int rL = wr * 64 + i * 16 + l16 * 4 + q;
      int rG = rowBase + rL;
      const float* ap = AB1 + (size_t)sIF[rL] * 2048;
      const float* bp = AB1 + (size_t)sIS[rL] * 2048 + 1024;
#pragma unroll
      for (int j = 0; j < 4; ++j) {
        int c = cols[j];
        float v = acc[i][j][q] + ap[c] + bp[c] + bv[j];
        h1out[(size_t)rG * 1024 + c] = (_Float16)fmaxf(v, 0.f);
      }
    }
}

// f32 -> f16 copy (n8 = elems/8)
__global__ __launch_bounds__(256) void cvt_f16(
    const float* __restrict__ in, _Float16* __restrict__ out, long long n8) {
  long long i = (long long)blockIdx.x * 256 + threadIdx.x;
  if (i >= n8) return;
  const float4* p = (const float4*)in + i * 2;
  float4 a = p[0], b = p[1];
  half8 h;
  h[0] = (_Float16)a.x; h[1] = (_Float16)a.y; h[2] = (_Float16)a.z; h[3] = (_Float16)a.w;
  h[4] = (_Float16)b.x; h[5] = (_Float16)b.y; h[6] = (_Float16)b.z; h[7] = (_Float16)b.w;
  *(half8*)(out + i * 8) = h;
}

// out[n][k] = (f16) in[k][n], 1024x1024
__global__ __launch_bounds__(256) void transpose_cvt(
    const float* __restrict__ in, _Float16* __restrict__ out) {
  __shared__ float t[32][33];
  const int tx = threadIdx.x & 31, ty = threadIdx.x >> 5;
  const int k0 = blockIdx.y * 32, n0 = blockIdx.x * 32;
#pragma unroll
  for (int q = 0; q < 4; ++q)
    t[ty + q * 8][tx] = in[(size_t)(k0 + ty + q * 8) * 1024 + n0 + tx];
  __syncthreads();
#pragma unroll
  for (int q = 0; q < 4; ++q)
    out[(size_t)(n0 + ty + q * 8) * 1024 + k0 + tx] = (_Float16)t[tx][ty + q * 8];
}

__global__ __launch_bounds__(256) void idx_init(int* __restrict__ idxF, int* __restrict__ idxS) {
  int r = blockIdx.x * 256 + threadIdx.x;
  if (r >= ROWS) return;
  int bb = r / NPAIR, p = r - bb * NPAIR;
  int cum = 0, f = 0;
  while (true) { int cnt = NS - 1 - f; if (p < cum + cnt) break; cum += cnt; ++f; }
  idxF[r] = bb * NS + f;
  idxS[r] = bb * NS + f + 1 + (p - cum);
}

__global__ void init_scores(float* __restrict__ scores, const float* __restrict__ b3) {
  int idx = blockIdx.x * 256 + threadIdx.x;
  if (idx < ROWS) scores[idx] = b3[0];
}

// grounding[b,n,l] = mask ? dotSI[b*48+n][b*36+l] : NEG
__global__ __launch_bounds__(256) void extract_grounding(
    const float* __restrict__ dotSI, const float* __restrict__ smask,
    const float* __restrict__ imask, float* __restrict__ outg) {
  int idx = blockIdx.x * 256 + threadIdx.x;
  if (idx >= B_ * NS * LI) return;
  int b = idx / (NS * LI);
  int rem = idx - b * (NS * LI);
  int n = rem / LI, l = rem - n * LI;
  float v = dotSI[(size_t)(b * NS + n) * (B_ * LI) + b * LI + l];
  outg[idx] = (smask[b * NS + n] * imask[b * LI + l] != 0.f) ? v : NEGV;
}

// ---------------------------------------------------------------------------
// Sentence scores S[i,j] (exp(NEG)==0 in f32 -> exact masked softmax)
// ---------------------------------------------------------------------------
__global__ __launch_bounds__(64) void sent_kernel(
    const float* __restrict__ dotTI, const float* __restrict__ tmask,
    const float* __restrict__ imask, float* __restrict__ S) {
  const int i = blockIdx.y, j = blockIdx.x, t = threadIdx.x;
  __shared__ float red1[64], red2[64];
  const int stride = B_ * LI;
  float e1 = 0.f;
  {
    float tm = tmask[i * NT + t];
    if (tm != 0.f) {
      const float* row = dotTI + (size_t)(i * NT + t) * stride + j * LI;
      float m = -INFINITY;
      for (int l = 0; l < LI; ++l) if (imask[j * LI + l] != 0.f) m = fmaxf(m, row[l]);
      float z = 0.f, w = 0.f;
      for (int l = 0; l < LI; ++l) if (imask[j * LI + l] != 0.f) {
        float d = row[l], p = expf(d - m);
        z += p; w += p * d;
      }
      e1 = w / z;
    }
  }
  red1[t] = e1;
  float e2 = 0.f;
  if (t < LI) {
    float im = imask[j * LI + t];
    if (im != 0.f) {
      const float* col = dotTI + (size_t)(i * NT) * stride + j * LI + t;
      float m = -INFINITY;
      for (int n = 0; n < NT; ++n) if (tmask[i * NT + n] != 0.f) m = fmaxf(m, col[(size_t)n * stride]);
      float z = 0.f, w = 0.f;
      for (int n = 0; n < NT; ++n) if (tmask[i * NT + n] != 0.f) {
        float d = col[(size_t)n * stride], p = expf(d - m);
        z += p; w += p * d;
      }
      e2 = w / z;
    }
  }
  red2[t] = e2;
  __syncthreads();
  if (t == 0) {
    float s1 = 0.f, s2 = 0.f, cn = 0.f, cl = 0.f;
    for (int n = 0; n < NT; ++n) { s1 += red1[n]; cn += tmask[i * NT + n]; }
    for (int l = 0; l < LI; ++l) { s2 += red2[l]; cl += imask[j * LI + l]; }
    S[i * B_ + j] = s1 / cn + s2 / cl;
  }
}

__global__ __launch_bounds__(64) void loss_kernel(
    const float* __restrict__ S, float* __restrict__ out) {
  __shared__ float sS[B_][B_ + 1];
  __shared__ float acc[B_];
  const int t = threadIdx.x;
  for (int e = t; e < B_ * B_; e += 64) sS[e / B_][e % B_] = S[e];
  __syncthreads();
  if (t < B_) {
    float m = -INFINITY;
    for (int j = 0; j < B_; ++j) m = fmaxf(m, sS[t][j]);
    float z = 0.f;
    for (int j = 0; j < B_; ++j) z += expf(sS[t][j] - m);
    float lr = m + logf(z);
    float m2 = -INFINITY;
    for (int i = 0; i < B_; ++i) m2 = fmaxf(m2, sS[i][t]);
    float z2 = 0.f;
    for (int i = 0; i < B_; ++i) z2 += expf(sS[i][t] - m2);
    float lc = m2 + logf(z2);
    acc[t] = 2.f * sS[t][t] - lr - lc;
  }
  __syncthreads();
  if (t == 0) {
    float s = 0.f;
    for (int i = 0; i < B_; ++i) s += acc[i];
    out[0] = -s / (float)B_;
  }
}

extern "C" void kernel_launch(void* const* d_in, const int* in_sizes, int n_in,
                              void* d_out, int out_size, void* d_ws, size_t ws_size,
                              hipStream_t stream) {
  const float* text  = (const float*)d_in[0];
  const float* span  = (const float*)d_in[1];
  const float* img   = (const float*)d_in[2];
  const float* tmask = (const float*)d_in[3];
  const float* smask = (const float*)d_in[4];
  const float* imask = (const float*)d_in[5];
  const float* W1    = (const float*)d_in[6];
  const float* b1    = (const float*)d_in[7];
  const float* W2    = (const float*)d_in[8];
  const float* b2    = (const float*)d_in[9];
  const float* W3    = (const float*)d_in[10];
  const float* b3    = (const float*)d_in[11];

  float* out     = (float*)d_out;
  float* outLoss = out;
  float* outG    = out + 1;
  float* outT    = out + 1 + (size_t)B_ * NS * LI;

  // ---- workspace layout (all 16B aligned) ----
  char* w = (char*)d_ws;
  float*    dotTI = (float*)w;            w += (size_t)(B_*NT) * (B_*LI) * 4;   // 9.4 MB
  float*    dotSI = (float*)w;            w += (size_t)(B_*NS) * (B_*LI) * 4;   // 7.1 MB
  float*    S     = (float*)w;            w += 1024 * 4;
  float*    AB1   = (float*)w;            w += (size_t)1536 * 2048 * 4;         // 12.6 MB
  _Float16* h1    = (_Float16*)w;         w += (size_t)ROWS * 1024 * 2;         // 74 MB
  _Float16* textH = (_Float16*)w;         w += (size_t)2048 * 1024 * 2;
  _Float16* spanH = (_Float16*)w;         w += (size_t)1536 * 1024 * 2;
  _Float16* imgH  = (_Float16*)w;         w += (size_t)1152 * 1024 * 2;
  _Float16* W1abT = (_Float16*)w;         w += (size_t)2048 * 1024 * 2;
  _Float16* W1cT  = (_Float16*)w;         w += (size_t)1024 * 1024 * 2;
  _Float16* W2T   = (_Float16*)w;         w += (size_t)1024 * 1024 * 2;
  int*      idxF  = (int*)w;              w += ROWS * 4;
  int*      idxS  = (int*)w;              w += ROWS * 4;
  (void)ws_size; (void)in_sizes; (void)n_in; (void)out_size;

  // ---- prep: conversions / transposes / indices ----
  cvt_f16<<<(2048 * 128 + 255) / 256, 256, 0, stream>>>(text, textH, 2048LL * 128);
  cvt_f16<<<(1536 * 128 + 255) / 256, 256, 0, stream>>>(span, spanH, 1536LL * 128);
  cvt_f16<<<(1152 * 128 + 255) / 256, 256, 0, stream>>>(img, imgH, 1152LL * 128);
  transpose_cvt<<<dim3(32, 32), 256, 0, stream>>>(W1, W1abT);                      // W1a^T
  transpose_cvt<<<dim3(32, 32), 256, 0, stream>>>(W1 + 1024 * 1024, W1abT + 1024 * 1024); // W1b^T
  transpose_cvt<<<dim3(32, 32), 256, 0, stream>>>(W1 + 2048 * 1024, W1cT);         // W1c^T
  transpose_cvt<<<dim3(32, 32), 256, 0, stream>>>(W2, W2T);
  idx_init<<<(ROWS + 255) / 256, 256, 0, stream>>>(idxF, idxS);

  // ---- 1) dotTI = text @ img^T -> S -> loss ----
  mfma_gemm<0, 0><<<dim3((B_*LI) / 128, (B_*NT) / 128), 256, 0, stream>>>(
      textH, imgH, dotTI, nullptr, nullptr, nullptr, B_ * LI, D_);
  sent_kernel<<<dim3(B_, B_), 64, 0, stream>>>(dotTI, tmask, imask, S);
  loss_kernel<<<1, 64, 0, stream>>>(S, outLoss);

  // ---- 2) grounding via full span-image GEMM + diagonal extract ----
  mfma_gemm<0, 0><<<dim3((B_*LI) / 128, (B_*NS) / 128), 256, 0, stream>>>(
      spanH, imgH, dotSI, nullptr, nullptr, nullptr, B_ * LI, D_);
  extract_grounding<<<(B_*NS*LI + 255) / 256, 256, 0, stream>>>(dotSI, smask, imask, outG);

  // ---- 3) pairwise MLP ----
  // AB1 = span @ [W1a | W1b]  (f32 out, 1536 x 2048)
  mfma_gemm<0, 0><<<dim3(2048 / 128, 1536 / 128), 256, 0, stream>>>(
      spanH, W1abT, AB1, nullptr, nullptr, nullptr, 2048, D_);

  // h1 = relu((span_f .* span_s) @ W1c + A1 + B1 + b1), fused pair product
  gemm1_fused<<<8 * CPX * 8, 256, 0, stream>>>(
      spanH, W1cT, AB1, b1, h1, idxF, idxS);

  // scores = relu(h1 @ W2 + b2) . W3 + b3
  init_scores<<<(ROWS + 255) / 256, 256, 0, stream>>>(outT, b3);
  mfma_gemm<2, 1><<<8 * CPX * 8, 256, 0, stream>>>(
      h1, W2T, nullptr, outT, b2, W3, 1024, H_);
}

// Round 6
// 331.103 us; speedup vs baseline: 10.2320x; 1.0695x over previous
//
#include <hip/hip_runtime.h>
#include <math.h>
#include <stdint.h>

#define B_    32
#define NT    64
#define NS    48
#define LI    36
#define D_    1024
#define H_    1024
#define NPAIR 1128            // 48*47/2
#define ROWS  (B_*NPAIR)      // 36096 = 282*128 = 141*256
#define NEGV  -9.0e9f
#define NROWT 282             // 128-row tiles
#define CPX   36              // ceil(282/8) row tiles per XCD (gemm1 remap)

typedef _Float16 half8 __attribute__((ext_vector_type(8)));
typedef float floatx4 __attribute__((ext_vector_type(4)));
typedef __attribute__((address_space(3))) uint32_t lds_u32;
typedef __attribute__((address_space(1))) const uint32_t glb_u32;

#define GLOAD16(src, dst) __builtin_amdgcn_global_load_lds((glb_u32*)(src), (lds_u32*)(dst), 16, 0, 0)

// ===========================================================================
// gemm2_8ph: scores[r] += sum_c relu((h1 @ W2T^T)[r,c] + b2[c]) * W3[c]
// 256x256 tile, BK=64, 8 waves (512 thr), 4 phases/K-tile, counted vmcnt(4),
// slot-XOR swizzle (phys_slot = slot ^ (row&7)), T5 setprio.
// M=36096 (141 tiles), N=1024 (4 tiles) -> 564 blocks, bijective XCD remap.
// ===========================================================================
#define MMQ(QR, QC)                                                            \
  {                                                                            \
    _Pragma("unroll") for (int i = 0; i < 4; ++i) {                            \
      _Pragma("unroll") for (int j = 0; j < 2; ++j) {                          \
        acc[QR * 4 + i][QC * 2 + j] = __builtin_amdgcn_mfma_f32_16x16x32_f16(  \
            aF[i][0], bF[j][0], acc[QR * 4 + i][QC * 2 + j], 0, 0, 0);         \
        acc[QR * 4 + i][QC * 2 + j] = __builtin_amdgcn_mfma_f32_16x16x32_f16(  \
            aF[i][1], bF[j][1], acc[QR * 4 + i][QC * 2 + j], 0, 0, 0);         \
      }                                                                        \
    }                                                                          \
  }

__global__ __launch_bounds__(512, 2) void gemm2_8ph(
    const _Float16* __restrict__ Am, const _Float16* __restrict__ Bt,
    float* __restrict__ scores, const float* __restrict__ bias,
    const float* __restrict__ W3) {
  // LDS: A panels [db][h][128][8 slots x 8 halves] at ((db*2+h)*8192),
  //      B panels same at +32768.  131072 B total.
  __shared__ __align__(16) _Float16 sP[65536];
  __shared__ float sRed[256][4];

  // bijective XCD remap of 564 blocks: q=70, r=4
  const int orig = blockIdx.x;
  const int xcd = orig & 7, pos = orig >> 3;
  const int wg = (xcd < 4 ? xcd * 71 : 284 + (xcd - 4) * 70) + pos;
  const int rowBase = (wg >> 2) * 256;
  const int colBase = (wg & 3) * 256;

  const int t = threadIdx.x;
  const int wave = t >> 6, lane = t & 63;
  const int wq_r = wave >> 2, wq_c = wave & 3;
  const int l15 = lane & 15, l16 = lane >> 4;
  const int sxor = l15 & 7;

  // staging source addresses (pre-swizzled global column per lane)
  const int srow0 = t >> 3, srow1 = (512 + t) >> 3;
  const int lcol0 = ((t & 7) ^ (srow0 & 7)) << 3;
  const int lcol1 = (((512 + t) & 7) ^ (srow1 & 7)) << 3;
  const _Float16* aS0 = Am + (size_t)(rowBase + srow0) * D_ + lcol0;
  const _Float16* aS1 = Am + (size_t)(rowBase + srow1) * D_ + lcol1;
  const _Float16* bS0 = Bt + (size_t)(colBase + srow0) * D_ + lcol0;
  const _Float16* bS1 = Bt + (size_t)(colBase + srow1) * D_ + lcol1;

  auto stgA = [&](int kt, int h) {
    const int db = kt & 1;
    const size_t so = (size_t)kt * 64 + (size_t)h * 128 * D_;
    _Float16* d = sP + ((db << 1) + h) * 8192;
    GLOAD16(aS0 + so, d + t * 8);
    GLOAD16(aS1 + so, d + 4096 + t * 8);
  };
  auto stgB = [&](int kt, int h) {
    const int db = kt & 1;
    const size_t so = (size_t)kt * 64 + (size_t)h * 128 * D_;
    _Float16* d = sP + 32768 + ((db << 1) + h) * 8192;
    GLOAD16(bS0 + so, d + t * 8);
    GLOAD16(bS1 + so, d + 4096 + t * 8);
  };

  // fragment read addressing
  const int aRdRow = (wq_r * 64 + l15) * 64;   // halves
  const int bRdRow = (wq_c * 32 + l15) * 64;
  const int rdSlot0 = ((l16) ^ sxor) << 3;       // ks=0: slot=l16
  const int rdSlot1 = ((4 + l16) ^ sxor) << 3;   // ks=1: slot=4+l16

  half8 aF[4][2], bF[2][2];
  floatx4 acc[8][4] = {};

  auto ldA = [&](int db, int qr) {
    const _Float16* p = sP + ((db << 1) + qr) * 8192 + aRdRow;
#pragma unroll
    for (int i = 0; i < 4; ++i) {
      aF[i][0] = *(const half8*)(p + i * 1024 + rdSlot0);
      aF[i][1] = *(const half8*)(p + i * 1024 + rdSlot1);
    }
  };
  auto ldB = [&](int db, int qc) {
    const _Float16* p = sP + 32768 + ((db << 1) + qc) * 8192 + bRdRow;
#pragma unroll
    for (int j = 0; j < 2; ++j) {
      bF[j][0] = *(const half8*)(p + j * 1024 + rdSlot0);
      bF[j][1] = *(const half8*)(p + j * 1024 + rdSlot1);
    }
  };

  // prologue: issue order must match steady state: B0(0),A1(0),A0(0),B1(0),B0(1),A1(1)
  stgB(0, 0); stgA(0, 1); stgA(0, 0); stgB(0, 1); stgB(1, 0); stgA(1, 1);
  asm volatile("s_waitcnt vmcnt(4)" ::: "memory");
  __builtin_amdgcn_s_barrier();

#pragma unroll 1
  for (int kt = 0; kt < 16; ++kt) {
    const int db = kt & 1;
    const int kn1 = (kt + 1) & 15, kn2 = (kt + 2) & 15;
    // ---- P0: quadrant (qr=0, qc=0); issue A0(kt+1)
    ldA(db, 0); ldB(db, 0);
    stgA(kn1, 0);
    __builtin_amdgcn_sched_barrier(0);
    __builtin_amdgcn_s_barrier();
    __builtin_amdgcn_s_setprio(1);
    MMQ(0, 0);
    __builtin_amdgcn_s_setprio(0);
    __builtin_amdgcn_s_barrier();
    // ---- P1: (1,0) reuse B; issue B1(kt+1)
    ldA(db, 1);
    stgB(kn1, 1);
    __builtin_amdgcn_sched_barrier(0);
    __builtin_amdgcn_s_barrier();
    __builtin_amdgcn_s_setprio(1);
    MMQ(1, 0);
    __builtin_amdgcn_s_setprio(0);
    __builtin_amdgcn_s_barrier();
    // ---- P2: (1,1) reuse A; issue B0(kt+2)
    ldB(db, 1);
    stgB(kn2, 0);
    __builtin_amdgcn_sched_barrier(0);
    __builtin_amdgcn_s_barrier();
    __builtin_amdgcn_s_setprio(1);
    MMQ(1, 1);
    __builtin_amdgcn_s_setprio(0);
    __builtin_amdgcn_s_barrier();
    // ---- P3: (0,1); issue A1(kt+2); K-tile boundary wait (never 0)
    ldA(db, 0);
    stgA(kn2, 1);
    __builtin_amdgcn_sched_barrier(0);
    asm volatile("s_waitcnt vmcnt(4)" ::: "memory");
    __builtin_amdgcn_s_barrier();
    __builtin_amdgcn_s_setprio(1);
    MMQ(0, 1);
    __builtin_amdgcn_s_setprio(0);
    __builtin_amdgcn_s_barrier();
  }

  // ---- epilogue: s = sum_c relu(acc + b2)*W3, reduce 16 lanes, 4 wq_c, atomic
  float bv[2][2], wv[2][2];
#pragma unroll
  for (int qc = 0; qc < 2; ++qc)
#pragma unroll
    for (int j = 0; j < 2; ++j) {
      int c = colBase + qc * 128 + wq_c * 32 + j * 16 + l15;
      bv[qc][j] = bias[c];
      wv[qc][j] = W3[c];
    }
#pragma unroll
  for (int qr = 0; qr < 2; ++qr)
#pragma unroll
    for (int i = 0; i < 4; ++i)
#pragma unroll
      for (int q = 0; q < 4; ++q) {
        float s = 0.f;
#pragma unroll
        for (int qc = 0; qc < 2; ++qc)
#pragma unroll
          for (int j = 0; j < 2; ++j)
            s += fmaxf(acc[qr * 4 + i][qc * 2 + j][q] + bv[qc][j], 0.f) * wv[qc][j];
        s += __shfl_xor(s, 1); s += __shfl_xor(s, 2);
        s += __shfl_xor(s, 4); s += __shfl_xor(s, 8);
        if (l15 == 0)
          sRed[qr * 128 + wq_r * 64 + i * 16 + l16 * 4 + q][wq_c] = s;
      }
  __syncthreads();
  if (t < 256)
    atomicAdd(&scores[rowBase + t],
              sRed[t][0] + sRed[t][1] + sRed[t][2] + sRed[t][3]);
}

// ===========================================================================
// Shared 128x128 EPI-0 GEMM body (R5 structure: BK=64, gload_lds, slot-XOR)
// ===========================================================================
__device__ __forceinline__ void gemm_body(
    const _Float16* __restrict__ A, const _Float16* __restrict__ Bt,
    float* __restrict__ Cf, int N, int K, int rowBase, int colBase) {
  __shared__ __align__(16) _Float16 sA[8192];
  __shared__ __align__(16) _Float16 sB[8192];
  const int tid = threadIdx.x;
  const int lane = tid & 63;
  const int wave = tid >> 6;
  const int wr = wave >> 1, wc = wave & 1;
  const int l15 = lane & 15, l16 = lane >> 4;
  const int rsw = (l15 >> 1) & 3;
  const int sRow = tid >> 2;
  const int swz8 = (((tid & 3) ^ ((tid >> 3) & 3)) << 3);
  const _Float16* gA = A + (size_t)(rowBase + sRow) * K + swz8;
  const _Float16* gB = Bt + (size_t)(colBase + sRow) * K + swz8;
  _Float16* lA = sA + tid * 8;
  _Float16* lB = sB + tid * 8;

  floatx4 acc[4][4] = {};
  for (int k0 = 0; k0 < K; k0 += 64) {
    GLOAD16(gA + k0,               lA);
    GLOAD16(gA + 64 * K + k0,      lA + 2048);
    GLOAD16(gA + k0 + 32,          lA + 4096);
    GLOAD16(gA + 64 * K + k0 + 32, lA + 6144);
    GLOAD16(gB + k0,               lB);
    GLOAD16(gB + 64 * K + k0,      lB + 2048);
    GLOAD16(gB + k0 + 32,          lB + 4096);
    GLOAD16(gB + 64 * K + k0 + 32, lB + 6144);
    __syncthreads();
#pragma unroll
    for (int h = 0; h < 2; ++h) {
      const int hb = h * 4096;
      half8 aF[4], bF[4];
#pragma unroll
      for (int i = 0; i < 4; ++i)
        aF[i] = *(const half8*)&sA[hb + (wr * 64 + i * 16 + l15) * 32 + ((l16 ^ rsw) << 3)];
#pragma unroll
      for (int j = 0; j < 4; ++j)
        bF[j] = *(const half8*)&sB[hb + (wc * 64 + j * 16 + l15) * 32 + ((l16 ^ rsw) << 3)];
#pragma unroll
      for (int i = 0; i < 4; ++i)
#pragma unroll
        for (int j = 0; j < 4; ++j)
          acc[i][j] = __builtin_amdgcn_mfma_f32_16x16x32_f16(aF[i], bF[j], acc[i][j], 0, 0, 0);
    }
    __syncthreads();
  }
#pragma unroll
  for (int i = 0; i < 4; ++i)
#pragma unroll
    for (int q = 0; q < 4; ++q) {
      int r = rowBase + wr * 64 + i * 16 + l16 * 4 + q;
#pragma unroll
      for (int j = 0; j < 4; ++j) {
        int c = colBase + wc * 64 + j * 16 + l15;
        Cf[(size_t)r * N + c] = acc[i][j][q];
      }
    }
}

// merged small GEMMs: dotTI (144 blk), dotSI (108), AB1 (192)
__global__ __launch_bounds__(256) void gemm_trio(
    const _Float16* __restrict__ textH, const _Float16* __restrict__ imgH,
    const _Float16* __restrict__ spanH, const _Float16* __restrict__ W1abT,
    float* __restrict__ dotTI, float* __restrict__ dotSI, float* __restrict__ AB1) {
  int bid = blockIdx.x;
  if (bid < 144)      gemm_body(textH, imgH, dotTI, 1152, D_, (bid / 9) * 128, (bid % 9) * 128);
  else if (bid < 252) { int b = bid - 144; gemm_body(spanH, imgH, dotSI, 1152, D_, (b / 9) * 128, (b % 9) * 128); }
  else                { int b = bid - 252; gemm_body(spanH, W1abT, AB1, 2048, D_, (b / 16) * 128, (b % 16) * 128); }
}

// ===========================================================================
// Fused GEMM1 (unchanged from R5): h1 = relu((spanF.*spanS)@W1c + A1+B1+b1)
// ===========================================================================
__global__ __launch_bounds__(256) void gemm1_fused(
    const _Float16* __restrict__ spanH, const _Float16* __restrict__ W1cT,
    const float* __restrict__ AB1, const float* __restrict__ b1,
    _Float16* __restrict__ h1out,
    const int* __restrict__ idxF, const int* __restrict__ idxS) {
  __shared__ __align__(16) _Float16 sF[8192];
  __shared__ __align__(16) _Float16 sS[8192];
  __shared__ __align__(16) _Float16 sB[8192];
  __shared__ int sIF[128], sIS[128];
  int bid = blockIdx.x;
  int x = bid & 7, ord = bid >> 3;
  int rowT = x * CPX + (ord >> 3);
  int colT = ord & 7;
  if (rowT >= NROWT) return;
  const int rowBase = rowT * 128, colBase = colT * 128;
  const int tid = threadIdx.x;
  const int lane = tid & 63;
  const int wave = tid >> 6;
  const int wr = wave >> 1, wc = wave & 1;
  const int l15 = lane & 15, l16 = lane >> 4;
  const int rsw = (l15 >> 1) & 3;

  if (tid < 128) {
    int rg = rowBase + tid;
    sIF[tid] = idxF[rg];
    sIS[tid] = idxS[rg];
  }
  __syncthreads();

  const int sRow = tid >> 2;
  const int swz8 = (((tid & 3) ^ ((tid >> 3) & 3)) << 3);
  const _Float16* gF0 = spanH + (size_t)sIF[sRow] * D_ + swz8;
  const _Float16* gF1 = spanH + (size_t)sIF[sRow + 64] * D_ + swz8;
  const _Float16* gS0 = spanH + (size_t)sIS[sRow] * D_ + swz8;
  const _Float16* gS1 = spanH + (size_t)sIS[sRow + 64] * D_ + swz8;
  const _Float16* gB  = W1cT + (size_t)(colBase + sRow) * D_ + swz8;
  _Float16* lF = sF + tid * 8;
  _Float16* lS = sS + tid * 8;
  _Float16* lB = sB + tid * 8;

  floatx4 acc[4][4] = {};
  for (int k0 = 0; k0 < D_; k0 += 64) {
    GLOAD16(gF0 + k0,      lF);
    GLOAD16(gF1 + k0,      lF + 2048);
    GLOAD16(gF0 + k0 + 32, lF + 4096);
    GLOAD16(gF1 + k0 + 32, lF + 6144);
    GLOAD16(gS0 + k0,      lS);
    GLOAD16(gS1 + k0,      lS + 2048);
    GLOAD16(gS0 + k0 + 32, lS + 4096);
    GLOAD16(gS1 + k0 + 32, lS + 6144);
    GLOAD16(gB + k0,               lB);
    GLOAD16(gB + 64 * D_ + k0,     lB + 2048);
    GLOAD16(gB + k0 + 32,          lB + 4096);
    GLOAD16(gB + 64 * D_ + k0 + 32,lB + 6144);
    __syncthreads();
#pragma unroll
    for (int h = 0; h < 2; ++h) {
      const int hb = h * 4096;
      half8 aF[4], bF[4];
#pragma unroll
      for (int i = 0; i < 4; ++i) {
        int off = hb + (wr * 64 + i * 16 + l15) * 32 + ((l16 ^ rsw) << 3);
        half8 f = *(const half8*)&sF[off];
        half8 s = *(const half8*)&sS[off];
        aF[i] = f * s;
      }
#pragma unroll
      for (int j = 0; j < 4; ++j)
        bF[j] = *(const half8*)&sB[hb + (wc * 64 + j * 16 + l15) * 32 + ((l16 ^ rsw) << 3)];
#pragma unroll
      for (int i = 0; i < 4; ++i)
#pragma unroll
        for (int j = 0; j < 4; ++j)
          acc[i][j] = __builtin_amdgcn_mfma_f32_16x16x32_f16(aF[i], bF[j], acc[i][j], 0, 0, 0);
    }
    __syncthreads();
  }

  int cols[4]; float bv[4];
#pragma unroll
  for (int j = 0; j < 4; ++j) {
    cols[j] = colBase + wc * 64 + j * 16 + l15;
    bv[j] = b1[cols[j]];
  }
#pragma unroll
  for (int i = 0; i < 4; ++i)
#pragma unroll
    for (int q = 0; q < 4; ++q) {
      int rL = wr * 64 + i * 16 + l16 * 4 + q;
      int rG = rowBase + rL;
      const float* ap = AB1 + (size_t)sIF[rL] * 2048;
      const float* bp = AB1 + (size_t)sIS[rL] * 2048 + 1024;
#pragma unroll
      for (int j = 0; j < 4; ++j) {
        int c = cols[j];
        float v = acc[i][j][q] + ap[c] + bp[c] + bv[j];
        h1out[(size_t)rG * 1024 + c] = (_Float16)fmaxf(v, 0.f);
      }
    }
}

// ===========================================================================
// prep / small kernels
// ===========================================================================
__global__ __launch_bounds__(256) void cvt_all(
    const float* __restrict__ text, const float* __restrict__ span,
    const float* __restrict__ img, _Float16* __restrict__ textH,
    _Float16* __restrict__ spanH, _Float16* __restrict__ imgH) {
  long long i = (long long)blockIdx.x * 256 + threadIdx.x;
  const float* src; _Float16* dst; long long off;
  if (i < 262144)      { src = text; dst = textH; off = i; }
  else if (i < 458752) { src = span; dst = spanH; off = i - 262144; }
  else if (i < 606208) { src = img;  dst = imgH;  off = i - 458752; }
  else return;
  const float4* p = (const float4*)src + off * 2;
  float4 a = p[0], b = p[1];
  half8 h;
  h[0] = (_Float16)a.x; h[1] = (_Float16)a.y; h[2] = (_Float16)a.z; h[3] = (_Float16)a.w;
  h[4] = (_Float16)b.x; h[5] = (_Float16)b.y; h[6] = (_Float16)b.z; h[7] = (_Float16)b.w;
  *(half8*)(dst + off * 8) = h;
}

__global__ __launch_bounds__(256) void transpose_all(
    const float* __restrict__ W1, const float* __restrict__ W2,
    _Float16* __restrict__ W1abT, _Float16* __restrict__ W1cT,
    _Float16* __restrict__ W2T) {
  __shared__ float tbuf[32][33];
  const float* in; _Float16* out;
  switch (blockIdx.z) {
    case 0: in = W1;                 out = W1abT;                 break;
    case 1: in = W1 + 1024 * 1024;   out = W1abT + 1024 * 1024;   break;
    case 2: in = W1 + 2048 * 1024;   out = W1cT;                  break;
    default: in = W2;                out = W2T;                   break;
  }
  const int tx = threadIdx.x & 31, ty = threadIdx.x >> 5;
  const int k0 = blockIdx.y * 32, n0 = blockIdx.x * 32;
#pragma unroll
  for (int q = 0; q < 4; ++q)
    tbuf[ty + q * 8][tx] = in[(size_t)(k0 + ty + q * 8) * 1024 + n0 + tx];
  __syncthreads();
#pragma unroll
  for (int q = 0; q < 4; ++q)
    out[(size_t)(n0 + ty + q * 8) * 1024 + k0 + tx] = (_Float16)tbuf[tx][ty + q * 8];
}

__global__ __launch_bounds__(256) void idx_init(int* __restrict__ idxF, int* __restrict__ idxS) {
  int r = blockIdx.x * 256 + threadIdx.x;
  if (r >= ROWS) return;
  int bb = r / NPAIR, p = r - bb * NPAIR;
  int cum = 0, f = 0;
  while (true) { int cnt = NS - 1 - f; if (p < cum + cnt) break; cum += cnt; ++f; }
  idxF[r] = bb * NS + f;
  idxS[r] = bb * NS + f + 1 + (p - cum);
}

__global__ void init_scores(float* __restrict__ scores, const float* __restrict__ b3) {
  int idx = blockIdx.x * 256 + threadIdx.x;
  if (idx < ROWS) scores[idx] = b3[0];
}

__global__ __launch_bounds__(256) void extract_grounding(
    const float* __restrict__ dotSI, const float* __restrict__ smask,
    const float* __restrict__ imask, float* __restrict__ outg) {
  int idx = blockIdx.x * 256 + threadIdx.x;
  if (idx >= B_ * NS * LI) return;
  int b = idx / (NS * LI);
  int rem = idx - b * (NS * LI);
  int n = rem / LI, l = rem - n * LI;
  float v = dotSI[(size_t)(b * NS + n) * (B_ * LI) + b * LI + l];
  outg[idx] = (smask[b * NS + n] * imask[b * LI + l] != 0.f) ? v : NEGV;
}

__global__ __launch_bounds__(64) void sent_kernel(
    const float* __restrict__ dotTI, const float* __restrict__ tmask,
    const float* __restrict__ imask, float* __restrict__ S) {
  const int i = blockIdx.y, j = blockIdx.x, t = threadIdx.x;
  __shared__ float red1[64], red2[64];
  const int stride = B_ * LI;
  float e1 = 0.f;
  {
    float tm = tmask[i * NT + t];
    if (tm != 0.f) {
      const float* row = dotTI + (size_t)(i * NT + t) * stride + j * LI;
      float m = -INFINITY;
      for (int l = 0; l < LI; ++l) if (imask[j * LI + l] != 0.f) m = fmaxf(m, row[l]);
      float z = 0.f, w = 0.f;
      for (int l = 0; l < LI; ++l) if (imask[j * LI + l] != 0.f) {
        float d = row[l], p = expf(d - m);
        z += p; w += p * d;
      }
      e1 = w / z;
    }
  }
  red1[t] = e1;
  float e2 = 0.f;
  if (t < LI) {
    float im = imask[j * LI + t];
    if (im != 0.f) {
      const float* col = dotTI + (size_t)(i * NT) * stride + j * LI + t;
      float m = -INFINITY;
      for (int n = 0; n < NT; ++n) if (tmask[i * NT + n] != 0.f) m = fmaxf(m, col[(size_t)n * stride]);
      float z = 0.f, w = 0.f;
      for (int n = 0; n < NT; ++n) if (tmask[i * NT + n] != 0.f) {
        float d = col[(size_t)n * stride], p = expf(d - m);
        z += p; w += p * d;
      }
      e2 = w / z;
    }
  }
  red2[t] = e2;
  __syncthreads();
  if (t == 0) {
    float s1 = 0.f, s2 = 0.f, cn = 0.f, cl = 0.f;
    for (int n = 0; n < NT; ++n) { s1 += red1[n]; cn += tmask[i * NT + n]; }
    for (int l = 0; l < LI; ++l) { s2 += red2[l]; cl += imask[j * LI + l]; }
    S[i * B_ + j] = s1 / cn + s2 / cl;
  }
}

__global__ __launch_bounds__(64) void loss_kernel(
    const float* __restrict__ S, float* __restrict__ out) {
  __shared__ float sS[B_][B_ + 1];
  __shared__ float acc[B_];
  const int t = threadIdx.x;
  for (int e = t; e < B_ * B_; e += 64) sS[e / B_][e % B_] = S[e];
  __syncthreads();
  if (t < B_) {
    float m = -INFINITY;
    for (int j = 0; j < B_; ++j) m = fmaxf(m, sS[t][j]);
    float z = 0.f;
    for (int j = 0; j < B_; ++j) z += expf(sS[t][j] - m);
    float lr = m + logf(z);
    float m2 = -INFINITY;
    for (int i = 0; i < B_; ++i) m2 = fmaxf(m2, sS[i][t]);
    float z2 = 0.f;
    for (int i = 0; i < B_; ++i) z2 += expf(sS[i][t] - m2);
    float lc = m2 + logf(z2);
    acc[t] = 2.f * sS[t][t] - lr - lc;
  }
  __syncthreads();
  if (t == 0) {
    float s = 0.f;
    for (int i = 0; i < B_; ++i) s += acc[i];
    out[0] = -s / (float)B_;
  }
}

extern "C" void kernel_launch(void* const* d_in, const int* in_sizes, int n_in,
                              void* d_out, int out_size, void* d_ws, size_t ws_size,
                              hipStream_t stream) {
  const float* text  = (const float*)d_in[0];
  const float* span  = (const float*)d_in[1];
  const float* img   = (const float*)d_in[2];
  const float* tmask = (const float*)d_in[3];
  const float* smask = (const float*)d_in[4];
  const float* imask = (const float*)d_in[5];
  const float* W1    = (const float*)d_in[6];
  const float* b1    = (const float*)d_in[7];
  const float* W2    = (const float*)d_in[8];
  const float* b2    = (const float*)d_in[9];
  const float* W3    = (const float*)d_in[10];
  const float* b3    = (const float*)d_in[11];

  float* out     = (float*)d_out;
  float* outLoss = out;
  float* outG    = out + 1;
  float* outT    = out + 1 + (size_t)B_ * NS * LI;

  // ---- workspace layout ----
  char* w = (char*)d_ws;
  float*    dotTI = (float*)w;            w += (size_t)(B_*NT) * (B_*LI) * 4;
  float*    dotSI = (float*)w;            w += (size_t)(B_*NS) * (B_*LI) * 4;
  float*    S     = (float*)w;            w += 1024 * 4;
  float*    AB1   = (float*)w;            w += (size_t)1536 * 2048 * 4;
  _Float16* h1    = (_Float16*)w;         w += (size_t)ROWS * 1024 * 2;
  _Float16* textH = (_Float16*)w;         w += (size_t)2048 * 1024 * 2;
  _Float16* spanH = (_Float16*)w;         w += (size_t)1536 * 1024 * 2;
  _Float16* imgH  = (_Float16*)w;         w += (size_t)1152 * 1024 * 2;
  _Float16* W1abT = (_Float16*)w;         w += (size_t)2048 * 1024 * 2;
  _Float16* W1cT  = (_Float16*)w;         w += (size_t)1024 * 1024 * 2;
  _Float16* W2T   = (_Float16*)w;         w += (size_t)1024 * 1024 * 2;
  int*      idxF  = (int*)w;              w += ROWS * 4;
  int*      idxS  = (int*)w;              w += ROWS * 4;
  (void)ws_size; (void)in_sizes; (void)n_in; (void)out_size;

  // ---- prep ----
  cvt_all<<<(606208 + 255) / 256, 256, 0, stream>>>(text, span, img, textH, spanH, imgH);
  transpose_all<<<dim3(32, 32, 4), 256, 0, stream>>>(W1, W2, W1abT, W1cT, W2T);
  idx_init<<<(ROWS + 255) / 256, 256, 0, stream>>>(idxF, idxS);

  // ---- small GEMMs merged: dotTI, dotSI, AB1 ----
  gemm_trio<<<444, 256, 0, stream>>>(textH, imgH, spanH, W1abT, dotTI, dotSI, AB1);
  sent_kernel<<<dim3(B_, B_), 64, 0, stream>>>(dotTI, tmask, imask, S);
  loss_kernel<<<1, 64, 0, stream>>>(S, outLoss);
  extract_grounding<<<(B_*NS*LI + 255) / 256, 256, 0, stream>>>(dotSI, smask, imask, outG);

  // ---- pairwise MLP ----
  gemm1_fused<<<8 * CPX * 8, 256, 0, stream>>>(spanH, W1cT, AB1, b1, h1, idxF, idxS);
  init_scores<<<(ROWS + 255) / 256, 256, 0, stream>>>(outT, b3);
  gemm2_8ph<<<564, 512, 0, stream>>>(h1, W2T, outT, b2, W3);
}